// Round 8
// baseline (553.290 us; speedup 1.0000x reference)
//
#include <hip/hip_runtime.h>
#include <cstdint>
#include <cstddef>

#define N_NODES 50000
#define M_PAD   50048   // 391 * 128
#define MB_TILES 391
#define N_EDGES 800000
#define N_GRAPH 256
#define Z_DIM   2304
#define NREP    16
#define POOL_TOT (N_GRAPH * (128 + 256 + 384))
// privatized pooling partials: per (m_tile, n_tile, gslot{0,1}, half{0,1}) x 128 cols
#define PP_L1 (MB_TILES * 1 * 2 * 2 * 128)   // 200192
#define PP_L2 (MB_TILES * 2 * 2 * 2 * 128)   // 400384
#define PP_L3 (MB_TILES * 3 * 2 * 2 * 128)   // 600576
#define PP_TOT (PP_L1 + PP_L2 + PP_L3)

static constexpr float LEAKY  = 0.01f;
static constexpr float BN_EPS = 1e-5f;
static constexpr float FNEG   = -3.4e38f;
static constexpr float FPOS   =  3.4e38f;

typedef short short8 __attribute__((ext_vector_type(8)));
typedef float floatx4 __attribute__((ext_vector_type(4)));
typedef unsigned long long ull;

__device__ __forceinline__ unsigned short f2b(float f) {
  union { float f; unsigned int u; } v; v.f = f;
  unsigned int u = v.u;
  unsigned int r = (u + 0x7FFFu + ((u >> 16) & 1u)) >> 16;
  return (unsigned short)r;
}
__device__ __forceinline__ float b2f(unsigned short h) {
  union { unsigned int u; float f; } v; v.u = ((unsigned int)h) << 16;
  return v.f;
}
__device__ __forceinline__ unsigned fkey(float x) {
  unsigned k = __float_as_uint(x);
  return k ^ ((k & 0x80000000u) ? 0xFFFFFFFFu : 0x80000000u);
}
__device__ __forceinline__ float kdec(unsigned k) {
  k ^= (k & 0x80000000u) ? 0x80000000u : 0xFFFFFFFFu;
  return __uint_as_float(k);
}

// ---------------- one-shot init ----------------

__global__ void init_all_kernel(int* __restrict__ cntR, int* __restrict__ gcnt,
                                float* __restrict__ sums_all,
                                unsigned* __restrict__ pmaxk, unsigned* __restrict__ pmink,
                                float* __restrict__ psumg) {
  const int i = blockIdx.x * blockDim.x + threadIdx.x;
  if (i < NREP * N_NODES) cntR[i] = 0;
  if (i < N_GRAPH) gcnt[i] = 0;
  if (i < 2 * (128 + 256 + 384)) sums_all[i] = 0.f;
  if (i < POOL_TOT) { pmaxk[i] = 0u; pmink[i] = 0xFFFFFFFFu; psumg[i] = 0.f; }
}

// ---------------- CSR build (replicated histogram/cursor) ----------------

__global__ void hist_rep_kernel(const int* __restrict__ idx, int* __restrict__ cntR, int n) {
  int i = blockIdx.x * blockDim.x + threadIdx.x;
  if (i < n) {
    const int rep = blockIdx.x & (NREP - 1);
    atomicAdd(&cntR[rep * N_NODES + idx[i]], 1);
  }
}

// scan phase 1 fused with replica combine.
__global__ __launch_bounds__(256) void scan1_fused_kernel(int* __restrict__ cntR,
                                                          int* __restrict__ out,
                                                          int* __restrict__ part, int n) {
  __shared__ int sm[256];
  const int t = threadIdx.x;
  const int base = blockIdx.x * 1024 + t * 4;
  int v[4] = {0, 0, 0, 0};
#pragma unroll
  for (int j = 0; j < 4; ++j) {
    const int d = base + j;
    if (d < n) {
      int s = 0;
#pragma unroll
      for (int r = 0; r < NREP; ++r) {
        const int c = cntR[r * N_NODES + d];
        cntR[r * N_NODES + d] = s;
        s += c;
      }
      v[j] = s;
    }
  }
  const int tsum = v[0] + v[1] + v[2] + v[3];
  sm[t] = tsum;
  __syncthreads();
  for (int off = 1; off < 256; off <<= 1) {
    int x = (t >= off) ? sm[t - off] : 0;
    __syncthreads();
    sm[t] += x;
    __syncthreads();
  }
  const int excl = sm[t] - tsum;
  if (base     < n) out[base]     = excl;
  if (base + 1 < n) out[base + 1] = excl + v[0];
  if (base + 2 < n) out[base + 2] = excl + v[0] + v[1];
  if (base + 3 < n) out[base + 3] = excl + v[0] + v[1] + v[2];
  if (t == 255) part[blockIdx.x] = sm[255];
}

__global__ __launch_bounds__(256) void scan2_kernel(int* __restrict__ part, int nb,
                                                    int* __restrict__ total_out) {
  __shared__ int sm[256];
  const int t = threadIdx.x;
  const int v = (t < nb) ? part[t] : 0;
  sm[t] = v;
  __syncthreads();
  for (int off = 1; off < 256; off <<= 1) {
    int x = (t >= off) ? sm[t - off] : 0;
    __syncthreads();
    sm[t] += x;
    __syncthreads();
  }
  if (t < nb) part[t] = sm[t] - v;
  if (t == 255) *total_out = sm[255];
}

__global__ void scan3_cursor_kernel(int* __restrict__ out, const int* __restrict__ part,
                                    int* __restrict__ cntR, int n) {
  int i = blockIdx.x * blockDim.x + threadIdx.x;
  if (i >= n) return;
  const int rp = out[i] + part[i >> 10];
  out[i] = rp;
#pragma unroll
  for (int r = 0; r < NREP; ++r) cntR[r * N_NODES + i] += rp;
}

__global__ void bucket_kernel(const int* __restrict__ src, const int* __restrict__ dst,
                              const float* __restrict__ ew, int* __restrict__ cntR,
                              ull* __restrict__ epack, int E) {
  int e = blockIdx.x * blockDim.x + threadIdx.x;
  if (e < E) {
    const int rep = blockIdx.x & (NREP - 1);
    const int d = dst[e];
    const int p = atomicAdd(&cntR[rep * N_NODES + d], 1);
    epack[p] = ((ull)__float_as_uint(ew[e]) << 32) | (unsigned)src[e];
  }
}

__global__ __launch_bounds__(256) void hist_batch_kernel(const int* __restrict__ idx,
                                                         int* __restrict__ cnt, int n) {
  __shared__ int lh[N_GRAPH];
  lh[threadIdx.x] = 0;
  __syncthreads();
  int i = blockIdx.x * blockDim.x + threadIdx.x;
  if (i < n) atomicAdd(&lh[idx[i]], 1);
  __syncthreads();
  const int v = lh[threadIdx.x];
  if (v) atomicAdd(&cnt[threadIdx.x], v);
}

__global__ __launch_bounds__(256) void scan256_kernel(const int* __restrict__ cnt,
                                                      int* __restrict__ gptr) {
  __shared__ int sm[256];
  const int t = threadIdx.x;
  const int v = cnt[t];
  sm[t] = v;
  __syncthreads();
  for (int off = 1; off < 256; off <<= 1) {
    int x = (t >= off) ? sm[t - off] : 0;
    __syncthreads();
    sm[t] += x;
    __syncthreads();
  }
  gptr[t] = sm[t] - v;
  if (t == 255) gptr[256] = sm[255];
}

// ---------------- prep ----------------

__global__ void cast_bf16_kernel(const float* __restrict__ in,
                                 unsigned short* __restrict__ out, int npair) {
  int i = blockIdx.x * blockDim.x + threadIdx.x;
  if (i >= npair) return;
  float2 v = *(const float2*)(in + 2 * (size_t)i);
  ((unsigned int*)out)[i] = (unsigned int)f2b(v.x) | ((unsigned int)f2b(v.y) << 16);
}

__global__ __launch_bounds__(256) void wt_build_kernel(
    const float* __restrict__ wrel, const float* __restrict__ wroot,
    const float* __restrict__ brel, const float* __restrict__ sums_prev,
    const float* __restrict__ gamma_prev, const float* __restrict__ beta_prev,
    unsigned short* __restrict__ wt, float* __restrict__ u, float* __restrict__ v,
    int K, int N) {
  __shared__ float redu[256];
  __shared__ float redv[256];
  const int n = blockIdx.x;
  const int K2 = 2 * K;
  const float inv_n = 1.f / (float)N_NODES;
  float us = 0.f, vs = 0.f;
  for (int k = threadIdx.x; k < K2; k += 256) {
    const int kk = (k < K) ? k : k - K;
    const float w = (k < K) ? wrel[(size_t)kk * N + n] : wroot[(size_t)kk * N + n];
    float sc = 1.f, sh = 0.f;
    if (sums_prev) {
      const float mu  = sums_prev[kk] * inv_n;
      const float var = sums_prev[K + kk] * inv_n - mu * mu;
      sc = rsqrtf(var + BN_EPS) * gamma_prev[kk];
      sh = beta_prev[kk] - mu * sc;
    }
    wt[(size_t)n * K2 + k] = f2b(w * sc);
    if (k < K) us += sh * w; else vs += sh * w;
  }
  redu[threadIdx.x] = us; redv[threadIdx.x] = vs;
  __syncthreads();
  for (int o = 128; o > 0; o >>= 1) {
    if (threadIdx.x < o) {
      redu[threadIdx.x] += redu[threadIdx.x + o];
      redv[threadIdx.x] += redv[threadIdx.x + o];
    }
    __syncthreads();
  }
  if (threadIdx.x == 0) { u[n] = redu[0]; v[n] = brel[n] + redv[0]; }
}

// ---------------- aggregation: MLP-maximized gather (at its pattern roofline) --------

template <int D>
__global__ void agg_bf16_kernel(const unsigned short* __restrict__ h,
                                const int* __restrict__ rowptr,
                                const ull* __restrict__ epack,
                                unsigned short* __restrict__ agg,
                                float* __restrict__ degw_out) {
  int gid  = blockIdx.x * blockDim.x + threadIdx.x;
  int node = gid >> 6;
  int lane = threadIdx.x & 63;
  if (node >= N_NODES) return;
  const int beg = rowptr[node], end = rowptr[node + 1];
  constexpr int NP = D / 128;
  float acc0[NP], acc1[NP];
#pragma unroll
  for (int i = 0; i < NP; ++i) { acc0[i] = 0.f; acc1[i] = 0.f; }
  float wsum = 0.f;

  for (int c0 = beg; c0 < end; c0 += 64) {
    const int cn = min(64, end - c0);
    ull pk = 0;  // pad: src=0, w=0
    if (lane < cn) pk = epack[c0 + lane];
    const int   su = (int)(unsigned)pk;
    const float wf = __uint_as_float((unsigned)(pk >> 32));
    const int ng = (cn + 7) >> 3;  // groups of 8, padded
    for (int g = 0; g < ng; ++g) {
      int ss[8]; float wv[8];
#pragma unroll
      for (int j = 0; j < 8; ++j) {
        ss[j] = __shfl(su, g * 8 + j);
        wv[j] = __shfl(wf, g * 8 + j);
      }
      unsigned uu[8][NP];
#pragma unroll
      for (int j = 0; j < 8; ++j) {
        const unsigned int* row = (const unsigned int*)(h + (size_t)ss[j] * D);
#pragma unroll
        for (int i = 0; i < NP; ++i) uu[j][i] = row[lane + 64 * i];
      }
#pragma unroll
      for (int j = 0; j < 8; ++j) {
        wsum += wv[j];
#pragma unroll
        for (int i = 0; i < NP; ++i) {
          acc0[i] += b2f((unsigned short)(uu[j][i] & 0xFFFF)) * wv[j];
          acc1[i] += b2f((unsigned short)(uu[j][i] >> 16)) * wv[j];
        }
      }
    }
  }

  unsigned int* o = (unsigned int*)(agg + (size_t)node * D);
#pragma unroll
  for (int i = 0; i < NP; ++i)
    o[lane + 64 * i] = (unsigned int)f2b(acc0[i]) | ((unsigned int)f2b(acc1[i]) << 16);
  if (degw_out != nullptr && lane == 0) degw_out[node] = wsum;
}

// ---------------- MFMA GEMM, DIRECT-REGISTER (no LDS staging, no barriers) ----------------
// Round-8 change: r7 post-mortem showed the kernel 9x above its MFMA floor with 16%
// occupancy — the barriered global_load_lds pipeline itself was the bottleneck. This
// GEMM's K-step strip is one 64B line per row, so direct global->register fragment
// loads are perfectly coalesced (4 lanes/line) and L1 captures the 2-wave sharing.
// LDS staging + all K-loop barriers deleted; 1-step register double-buffer (named
// sets, unroll-2, rule #20); compiler schedules loads against MFMAs (m97 evidence).
// LDS 51.2KB -> 2KB; launch_bounds(256,3) caps VGPR ~170 for 3 waves/SIMD.
// Epilogue: single-pass register pooling (validated r7) unchanged.

__global__ __launch_bounds__(256, 3) void gemm_mfma_kernel(
    const unsigned short* __restrict__ Aagg, const unsigned short* __restrict__ Ah,
    const unsigned short* __restrict__ Wt,
    const float* __restrict__ u, const float* __restrict__ v,
    const float* __restrict__ degw, const int* __restrict__ batch,
    unsigned short* __restrict__ outH, float* __restrict__ sums,
    unsigned* __restrict__ pmaxk, unsigned* __restrict__ pmink,
    float* __restrict__ psumg,
    float* __restrict__ ppmax, float* __restrict__ ppmin, float* __restrict__ ppsum,
    int M, int K, int N) {
  __shared__ float col_s[256];
  __shared__ float dws[128];
  __shared__ int gbs[128];

  const int NT = N >> 7;
  const int id = blockIdx.x;
  const int xcd = id & 7;
  const int q   = id >> 3;
  const int m_tile = (q / NT) * 8 + xcd;
  if (m_tile >= MB_TILES) return;
  const int m0 = m_tile * 128;
  const int nt2 = q % NT;
  const int n0 = nt2 * 128;

  const int t  = threadIdx.x;
  const int lane = t & 63;
  const int w    = t >> 6;
  const int wm   = (w & 1) * 64;
  const int wn   = (w >> 1) * 64;
  const int l16  = lane & 15;
  const int lq   = lane >> 4;
  const int K2   = 2 * K;

  col_s[t] = 0.f;
  if (t < 128) {
    const int m = m0 + t;
    dws[t] = (m < M) ? degw[m] : 0.f;
    gbs[t] = (m < M) ? batch[m] : -1;
  }
  __syncthreads();  // dws/gbs/col_s ready before epilogue (no K-loop barriers anymore)

  floatx4 acc[4][4];
#pragma unroll
  for (int i = 0; i < 4; ++i)
#pragma unroll
    for (int j = 0; j < 4; ++j) acc[i][j] = (floatx4){0.f, 0.f, 0.f, 0.f};

  // per-lane fragment base pointers: row (m0+wm+l16), k-subchunk lq*8 of each 32-k step
  const unsigned short* ApA = Aagg + (size_t)(m0 + wm + l16) * K + lq * 8;
  const unsigned short* ApH = Ah   + (size_t)(m0 + wm + l16) * K + lq * 8;
  const unsigned short* Bp  = Wt   + (size_t)(n0 + wn + l16) * K2 + lq * 8;

  short8 afA[4], bfA[4], afB[4], bfB[4];

  auto loadf = [&](short8* af, short8* bf, int s) {
    const int k0 = s << 5;
    const unsigned short* Ap = (k0 < K) ? (ApA + k0) : (ApH + (k0 - K));
#pragma unroll
    for (int i = 0; i < 4; ++i)
      af[i] = *(const short8*)(Ap + (size_t)(i * 16) * K);
    const unsigned short* Bq = Bp + k0;
#pragma unroll
    for (int j = 0; j < 4; ++j)
      bf[j] = *(const short8*)(Bq + (size_t)(j * 16) * K2);
  };
  auto mf16 = [&](short8* af, short8* bf) {
    __builtin_amdgcn_s_setprio(1);
#pragma unroll
    for (int i = 0; i < 4; ++i)
#pragma unroll
      for (int j = 0; j < 4; ++j)
        acc[i][j] = __builtin_amdgcn_mfma_f32_16x16x32_bf16(af[i], bf[j], acc[i][j], 0, 0, 0);
    __builtin_amdgcn_s_setprio(0);
  };

  const int NSTEP = K2 >> 5;  // 8 or 16, always even

  loadf(afA, bfA, 0);
  for (int s = 0; s < NSTEP; s += 2) {
    loadf(afB, bfB, s + 1);       // prefetch next step into the other reg set
    mf16(afA, bfA);
    if (s + 2 < NSTEP) loadf(afA, bfA, s + 2);
    mf16(afB, bfB);
  }

  float uu[4], vv[4];
#pragma unroll
  for (int j = 0; j < 4; ++j) {
    const int n = n0 + wn + j * 16 + l16;
    uu[j] = u[n]; vv[j] = v[n];
  }

  // ---- single-pass epilogue: activation + hp write + BN sums + register pooling ----
  const bool wout = (outH != nullptr);
  const int lastr = min(127, M - 1 - m0);
  const int gmin = gbs[0];
  const int gmax = gbs[lastr];

  float ts[4]  = {0.f, 0.f, 0.f, 0.f};
  float tss[4] = {0.f, 0.f, 0.f, 0.f};
  float px0[4], pn0[4], ps0[4], px1[4], pn1[4], ps1[4];
#pragma unroll
  for (int j = 0; j < 4; ++j) {
    px0[j] = FNEG; pn0[j] = FPOS; ps0[j] = 0.f;
    px1[j] = FNEG; pn1[j] = FPOS; ps1[j] = 0.f;
  }

#pragma unroll
  for (int i = 0; i < 4; ++i) {
    const int lrow2 = wm + i * 16 + lq * 4;
#pragma unroll
    for (int r = 0; r < 4; ++r) {
      const int row = lrow2 + r;
      const bool live = (m0 + row < M);
      const int gv = gbs[row];
      const float dwr = dws[row];
      const bool in0 = live && (gv == gmin);
      const bool in1 = live && (gmax != gmin) && (gv == gmax);
#pragma unroll
      for (int j = 0; j < 4; ++j) {
        const int n = n0 + wn + j * 16 + l16;
        float val = acc[i][j][r] + vv[j] + dwr * uu[j];
        val = val > 0.f ? val : LEAKY * val;
        acc[i][j][r] = val;
        if (live) {
          if (wout) outH[(size_t)(m0 + row) * N + n] = f2b(val);
          ts[j]  += val;
          tss[j] += val * val;
        }
        if (in0) { px0[j] = fmaxf(px0[j], val); pn0[j] = fminf(pn0[j], val); ps0[j] += val; }
        if (in1) { px1[j] = fmaxf(px1[j], val); pn1[j] = fminf(pn1[j], val); ps1[j] += val; }
      }
    }
  }

  const int half = w & 1;
#pragma unroll
  for (int j = 0; j < 4; ++j) {
    float a = ts[j], b = tss[j];
    a += __shfl_xor(a, 16); a += __shfl_xor(a, 32);
    b += __shfl_xor(b, 16); b += __shfl_xor(b, 32);
    float x0 = px0[j], n0v = pn0[j], s0v = ps0[j];
    x0 = fmaxf(x0, __shfl_xor(x0, 16)); x0 = fmaxf(x0, __shfl_xor(x0, 32));
    n0v = fminf(n0v, __shfl_xor(n0v, 16)); n0v = fminf(n0v, __shfl_xor(n0v, 32));
    s0v += __shfl_xor(s0v, 16); s0v += __shfl_xor(s0v, 32);
    float x1 = px1[j], n1v = pn1[j], s1v = ps1[j];
    x1 = fmaxf(x1, __shfl_xor(x1, 16)); x1 = fmaxf(x1, __shfl_xor(x1, 32));
    n1v = fminf(n1v, __shfl_xor(n1v, 16)); n1v = fminf(n1v, __shfl_xor(n1v, 32));
    s1v += __shfl_xor(s1v, 16); s1v += __shfl_xor(s1v, 32);
    if (lane < 16) {
      const int ci = wn + j * 16 + l16;
      atomicAdd(&col_s[ci], a);
      atomicAdd(&col_s[128 + ci], b);
      const size_t tb = (size_t)(m_tile * NT + nt2) * 2;
      const size_t sb0 = ((tb + 0) * 2 + half) * 128 + ci;
      const size_t sb1 = ((tb + 1) * 2 + half) * 128 + ci;
      ppmax[sb0] = x0;  ppmin[sb0] = n0v; ppsum[sb0] = s0v;
      ppmax[sb1] = x1;  ppmin[sb1] = n1v; ppsum[sb1] = s1v;
    }
  }

  // cold fallback: block spans >2 graphs (never for ~195-row graphs) -> global atomics
  if (gmax > gmin + 1) {
    for (int g = gmin + 1; g < gmax; ++g) {
#pragma unroll
      for (int j = 0; j < 4; ++j) {
        float mx = FNEG, mn = FPOS, sm = 0.f;
#pragma unroll
        for (int i = 0; i < 4; ++i) {
          const int lrow2 = wm + i * 16 + lq * 4;
#pragma unroll
          for (int r = 0; r < 4; ++r) {
            const int row = lrow2 + r;
            if (m0 + row < M && gbs[row] == g) {
              const float val = acc[i][j][r];
              mx = fmaxf(mx, val); mn = fminf(mn, val); sm += val;
            }
          }
        }
        mx = fmaxf(mx, __shfl_xor(mx, 16)); mx = fmaxf(mx, __shfl_xor(mx, 32));
        mn = fminf(mn, __shfl_xor(mn, 16)); mn = fminf(mn, __shfl_xor(mn, 32));
        sm += __shfl_xor(sm, 16); sm += __shfl_xor(sm, 32);
        if (lane < 16 && mx > -3.3e38f) {
          const size_t pi = (size_t)g * N + (n0 + wn + j * 16 + l16);
          atomicMax(&pmaxk[pi], fkey(mx));
          atomicMin(&pmink[pi], fkey(mn));
          atomicAdd(&psumg[pi], sm);
        }
      }
    }
  }

  __syncthreads();
  if (t < 128) {
    atomicAdd(&sums[n0 + t], col_s[t]);
    atomicAdd(&sums[N + n0 + t], col_s[128 + t]);
  }
}

// ---------------- combined pool finalize: merge privatized partials + fallback ----------

__global__ void pool_finalize_all_kernel(const unsigned* __restrict__ pmaxk,
                                         const unsigned* __restrict__ pmink,
                                         const float* __restrict__ psumg,
                                         const float* __restrict__ ppmax,
                                         const float* __restrict__ ppmin,
                                         const float* __restrict__ ppsum,
                                         const float* __restrict__ sums_all,
                                         const float* __restrict__ gamma1, const float* __restrict__ beta1,
                                         const float* __restrict__ gamma2, const float* __restrict__ beta2,
                                         const float* __restrict__ gamma3, const float* __restrict__ beta3,
                                         const int* __restrict__ gptr,
                                         const int* __restrict__ batch,
                                         float* __restrict__ z) {
  int i = blockIdx.x * blockDim.x + threadIdx.x;
  if (i >= POOL_TOT) return;
  int C, zoff, li, NTL;
  size_t ppo;
  const float *sums, *gamma, *beta;
  if (i < N_GRAPH * 128) {
    C = 128; zoff = 0; li = i; NTL = 1; ppo = 0;
    sums = sums_all; gamma = gamma1; beta = beta1;
  } else if (i < N_GRAPH * (128 + 256)) {
    C = 256; zoff = 384; li = i - N_GRAPH * 128; NTL = 2; ppo = PP_L1;
    sums = sums_all + 2 * 128; gamma = gamma2; beta = beta2;
  } else {
    C = 384; zoff = 1152; li = i - N_GRAPH * (128 + 256); NTL = 3; ppo = PP_L1 + PP_L2;
    sums = sums_all + 2 * (128 + 256); gamma = gamma3; beta = beta3;
  }
  const int g = li / C, c = li % C;
  const int cnt = gptr[g + 1] - gptr[g];

  // merge fallback atomics (neutral unless a block spanned >2 graphs)
  float mx = FNEG, mn = FPOS, sm = psumg[i];
  {
    const unsigned pk = pmaxk[i];
    if (pk != 0u) mx = kdec(pk);
    const unsigned nk = pmink[i];
    if (nk != 0xFFFFFFFFu) mn = kdec(nk);
  }
  // merge privatized per-(m_tile, gslot, half) partials
  if (cnt > 0) {
    const int mt_lo = gptr[g] >> 7;
    const int mt_hi = (gptr[g + 1] - 1) >> 7;
    const int nt = c >> 7, cc = c & 127;
    for (int mt = mt_lo; mt <= mt_hi; ++mt) {
      const int g0 = batch[mt << 7];
      int grel = (g == g0) ? 0 : -1;
      if (grel < 0) {
        const int lastm = min((mt << 7) + 127, N_NODES - 1);
        if (g == batch[lastm]) grel = 1;
      }
      if (grel >= 0) {
        const size_t b0 = ppo + (((size_t)(mt * NTL + nt) * 2 + grel) * 2 + 0) * 128 + cc;
        const size_t b1 = b0 + 128;
        mx = fmaxf(mx, fmaxf(ppmax[b0], ppmax[b1]));
        mn = fminf(mn, fminf(ppmin[b0], ppmin[b1]));
        sm += ppsum[b0] + ppsum[b1];
      }
    }
  }

  const float inv_n = 1.f / (float)N_NODES;
  const float mu  = sums[c] * inv_n;
  const float var = sums[C + c] * inv_n - mu * mu;
  const float sc  = rsqrtf(var + BN_EPS) * gamma[c];
  const float sh  = beta[c] - mu * sc;
  const float zmax = (sc >= 0.f ? mx : mn) * sc + sh;
  const float zsum = sm * sc + (float)cnt * sh;
  float* zg = z + (size_t)g * Z_DIM + zoff;
  zg[c]         = (cnt > 0) ? zmax : 0.f;
  zg[C + c]     = zsum / (float)(cnt > 0 ? cnt : 1);
  zg[2 * C + c] = zsum;
}

// ---------------- FC head ----------------

__global__ __launch_bounds__(1024) void fc_kernel(const float* __restrict__ z,
                                                  const float* __restrict__ w1, const float* __restrict__ b1,
                                                  const float* __restrict__ w2, const float* __restrict__ b2,
                                                  const float* __restrict__ w3, const float* __restrict__ b3,
                                                  float* __restrict__ out) {
  __shared__ float zs[Z_DIM];
  __shared__ float part[8][128];
  __shared__ float h1s[128];
  __shared__ float red[128][2];
  __shared__ float y2[2];
  const int g  = blockIdx.x;
  const int t  = threadIdx.x;
  const int c  = t & 127;
  const int ks = t >> 7;
  for (int i = t; i < Z_DIM; i += 1024) zs[i] = z[(size_t)g * Z_DIM + i];
  __syncthreads();

  constexpr int KCH = Z_DIM / 8;
  const int k0 = ks * KCH;
  float acc = 0.f;
#pragma unroll 4
  for (int k = k0; k < k0 + KCH; ++k) acc += zs[k] * w1[(size_t)k * 128 + c];
  part[ks][c] = acc;
  __syncthreads();

  if (t < 128) {
    float s = b1[t];
#pragma unroll
    for (int i = 0; i < 8; ++i) s += part[i][t];
    h1s[t] = fmaxf(s, 0.f);
  }
  __syncthreads();
  if (t < 128) {
    red[t][0] = h1s[t] * w2[t * 2 + 0];
    red[t][1] = h1s[t] * w2[t * 2 + 1];
  }
  __syncthreads();
  if (t < 2) {
    float s = b2[t];
    for (int k = 0; k < 128; ++k) s += red[k][t];
    y2[t] = fmaxf(s, 0.f);
  }
  __syncthreads();
  if (t == 0) {
    const float z0 = y2[0] * w3[0] + y2[1] * w3[2] + b3[0];
    const float z1 = y2[0] * w3[1] + y2[1] * w3[3] + b3[1];
    const float m  = fmaxf(z0, z1);
    const float lse = m + logf(expf(z0 - m) + expf(z1 - m));
    out[g * 2 + 0] = z0 - lse;
    out[g * 2 + 1] = z1 - lse;
  }
}

// ---------------- launch ----------------

extern "C" void kernel_launch(void* const* d_in, const int* in_sizes, int n_in,
                              void* d_out, int out_size, void* d_ws, size_t ws_size,
                              hipStream_t stream) {
  (void)in_sizes; (void)n_in; (void)out_size; (void)ws_size;
  const float* x        = (const float*)d_in[0];
  const int*   eidx     = (const int*)d_in[1];
  const int*   batch    = (const int*)d_in[2];
  const float* eattr    = (const float*)d_in[3];
  const float* w_rel1   = (const float*)d_in[4];
  const float* b_rel1   = (const float*)d_in[5];
  const float* w_root1  = (const float*)d_in[6];
  const float* w_rel2   = (const float*)d_in[7];
  const float* b_rel2   = (const float*)d_in[8];
  const float* w_root2  = (const float*)d_in[9];
  const float* w_rel3   = (const float*)d_in[10];
  const float* b_rel3   = (const float*)d_in[11];
  const float* w_root3  = (const float*)d_in[12];
  const float* gamma1   = (const float*)d_in[13];
  const float* beta1    = (const float*)d_in[14];
  const float* gamma2   = (const float*)d_in[15];
  const float* beta2    = (const float*)d_in[16];
  const float* gamma3   = (const float*)d_in[17];
  const float* beta3    = (const float*)d_in[18];
  const float* w_lin1   = (const float*)d_in[19];
  const float* b_lin1   = (const float*)d_in[20];
  const float* w_lin2   = (const float*)d_in[21];
  const float* b_lin2   = (const float*)d_in[22];
  const float* w_lin3   = (const float*)d_in[23];
  const float* b_lin3   = (const float*)d_in[24];

  const int* src = eidx;
  const int* dst = eidx + N_EDGES;
  float* outp = (float*)d_out;

  char* ws = (char*)d_ws;
  size_t off = 0;
  auto alloc = [&](size_t bytes) -> void* {
    void* p = ws + off;
    off += (bytes + 255) & ~(size_t)255;
    return p;
  };
  int*   rowptr = (int*)alloc((N_NODES + 1) * sizeof(int));
  int*   cntR   = (int*)alloc((size_t)NREP * N_NODES * sizeof(int));
  int*   gptr   = (int*)alloc((N_GRAPH + 1) * sizeof(int));
  int*   gcnt   = (int*)alloc(N_GRAPH * sizeof(int));
  int*   part   = (int*)alloc(256 * sizeof(int));
  ull*   epack  = (ull*)alloc((size_t)N_EDGES * sizeof(ull));
  float* degw   = (float*)alloc(N_NODES * sizeof(float));
  float* sums_all = (float*)alloc(2 * (128 + 256 + 384) * sizeof(float));
  float* zbuf   = (float*)alloc((size_t)N_GRAPH * Z_DIM * sizeof(float));
  unsigned* pmaxk = (unsigned*)alloc((size_t)POOL_TOT * 4);
  unsigned* pmink = (unsigned*)alloc((size_t)POOL_TOT * 4);
  float*    psumg = (float*)alloc((size_t)POOL_TOT * 4);
  float* ppmax = (float*)alloc((size_t)PP_TOT * 4);
  float* ppmin = (float*)alloc((size_t)PP_TOT * 4);
  float* ppsum = (float*)alloc((size_t)PP_TOT * 4);
  unsigned short* xb   = (unsigned short*)alloc((size_t)M_PAD * 128 * 2);
  unsigned short* hp1  = (unsigned short*)alloc((size_t)M_PAD * 128 * 2);
  unsigned short* hp2  = (unsigned short*)alloc((size_t)M_PAD * 256 * 2);
  unsigned short* aggb = (unsigned short*)alloc((size_t)M_PAD * 256 * 2);
  unsigned short* wt1 = (unsigned short*)alloc((size_t)128 * 256 * 2);
  unsigned short* wt2 = (unsigned short*)alloc((size_t)256 * 256 * 2);
  unsigned short* wt3 = (unsigned short*)alloc((size_t)384 * 512 * 2);
  float* u1 = (float*)alloc(128 * sizeof(float));
  float* v1 = (float*)alloc(128 * sizeof(float));
  float* u2 = (float*)alloc(256 * sizeof(float));
  float* v2 = (float*)alloc(256 * sizeof(float));
  float* u3 = (float*)alloc(384 * sizeof(float));
  float* v3 = (float*)alloc(384 * sizeof(float));

  float* sums1 = sums_all;
  float* sums2 = sums_all + 2 * 128;
  float* sums3 = sums_all + 2 * (128 + 256);
  const int PO1 = 0, PO2 = N_GRAPH * 128, PO3 = N_GRAPH * (128 + 256);

  const int EB = (N_EDGES + 255) / 256;
  const int NB = (N_NODES + 255) / 256;
  const int SB = (N_NODES + 1023) / 1024;

  init_all_kernel<<<(NREP * N_NODES + 255) / 256, 256, 0, stream>>>(
      cntR, gcnt, sums_all, pmaxk, pmink, psumg);

  // ---- CSR by dst ----
  hist_rep_kernel<<<EB, 256, 0, stream>>>(dst, cntR, N_EDGES);
  scan1_fused_kernel<<<SB, 256, 0, stream>>>(cntR, rowptr, part, N_NODES);
  scan2_kernel<<<1, 256, 0, stream>>>(part, SB, rowptr + N_NODES);
  scan3_cursor_kernel<<<NB, 256, 0, stream>>>(rowptr, part, cntR, N_NODES);
  bucket_kernel<<<EB, 256, 0, stream>>>(src, dst, eattr, cntR, epack, N_EDGES);

  // ---- graph segment pointers ----
  hist_batch_kernel<<<NB, 256, 0, stream>>>(batch, gcnt, N_NODES);
  scan256_kernel<<<1, 256, 0, stream>>>(gcnt, gptr);

  // ---- prep ----
  cast_bf16_kernel<<<(N_NODES * 128 / 2 + 255) / 256, 256, 0, stream>>>(x, xb, N_NODES * 128 / 2);
  wt_build_kernel<<<128, 256, 0, stream>>>(w_rel1, w_root1, b_rel1, nullptr, nullptr, nullptr,
                                           wt1, u1, v1, 128, 128);

  const int aggBlocks = (N_NODES * 64 + 255) / 256;

  // ---- layer 1: 128 -> 128 ----
  agg_bf16_kernel<128><<<aggBlocks, 256, 0, stream>>>(xb, rowptr, epack, aggb, degw);
  gemm_mfma_kernel<<<392 * 1, 256, 0, stream>>>(aggb, xb, wt1, u1, v1, degw, batch,
                                                hp1, sums1, pmaxk + PO1, pmink + PO1,
                                                psumg + PO1, ppmax, ppmin, ppsum,
                                                N_NODES, 128, 128);
  wt_build_kernel<<<256, 256, 0, stream>>>(w_rel2, w_root2, b_rel2, sums1, gamma1, beta1,
                                           wt2, u2, v2, 128, 256);

  // ---- layer 2: 128 -> 256 ----
  agg_bf16_kernel<128><<<aggBlocks, 256, 0, stream>>>(hp1, rowptr, epack, aggb, nullptr);
  gemm_mfma_kernel<<<392 * 2, 256, 0, stream>>>(aggb, hp1, wt2, u2, v2, degw, batch,
                                                hp2, sums2, pmaxk + PO2, pmink + PO2,
                                                psumg + PO2, ppmax + PP_L1, ppmin + PP_L1,
                                                ppsum + PP_L1, N_NODES, 128, 256);
  wt_build_kernel<<<384, 256, 0, stream>>>(w_rel3, w_root3, b_rel3, sums2, gamma2, beta2,
                                           wt3, u3, v3, 256, 384);

  // ---- layer 3: 256 -> 384 (no hp3 write: pooling fused, output unused) ----
  agg_bf16_kernel<256><<<aggBlocks, 256, 0, stream>>>(hp2, rowptr, epack, aggb, nullptr);
  gemm_mfma_kernel<<<392 * 3, 256, 0, stream>>>(aggb, hp2, wt3, u3, v3, degw, batch,
                                                (unsigned short*)nullptr, sums3,
                                                pmaxk + PO3, pmink + PO3, psumg + PO3,
                                                ppmax + PP_L1 + PP_L2, ppmin + PP_L1 + PP_L2,
                                                ppsum + PP_L1 + PP_L2, N_NODES, 256, 384);

  // ---- combined pool finalize (all layers) + FC head ----
  pool_finalize_all_kernel<<<(POOL_TOT + 255) / 256, 256, 0, stream>>>(
      pmaxk, pmink, psumg, ppmax, ppmin, ppsum, sums_all,
      gamma1, beta1, gamma2, beta2, gamma3, beta3, gptr, batch, zbuf);
  fc_kernel<<<N_GRAPH, 1024, 0, stream>>>(zbuf, w_lin1, b_lin1, w_lin2, b_lin2, w_lin3, b_lin3,
                                          outp);
}

// Round 9
// 510.223 us; speedup vs baseline: 1.0844x; 1.0844x over previous
//
#include <hip/hip_runtime.h>
#include <cstdint>
#include <cstddef>

#define N_NODES 50000
#define M_PAD   50048   // 391 * 128
#define MB_TILES 391
#define N_EDGES 800000
#define N_GRAPH 256
#define Z_DIM   2304
#define NREP    16
#define POOL_TOT (N_GRAPH * (128 + 256 + 384))
// privatized pooling partials: per (m_tile, n_tile, gslot{0,1}, half{0,1}) x 128 cols
#define PP_L1 (MB_TILES * 1 * 2 * 2 * 128)   // 200192
#define PP_L2 (MB_TILES * 2 * 2 * 2 * 128)   // 400384
#define PP_L3 (MB_TILES * 3 * 2 * 2 * 128)   // 600576
#define PP_TOT (PP_L1 + PP_L2 + PP_L3)

static constexpr float LEAKY  = 0.01f;
static constexpr float BN_EPS = 1e-5f;
static constexpr float FNEG   = -3.4e38f;
static constexpr float FPOS   =  3.4e38f;

typedef short short8 __attribute__((ext_vector_type(8)));
typedef float floatx4 __attribute__((ext_vector_type(4)));
typedef const __attribute__((address_space(1))) unsigned int* gas_ptr;
typedef __attribute__((address_space(3))) unsigned int* las_ptr;
typedef unsigned long long ull;

__device__ __forceinline__ unsigned short f2b(float f) {
  union { float f; unsigned int u; } v; v.f = f;
  unsigned int u = v.u;
  unsigned int r = (u + 0x7FFFu + ((u >> 16) & 1u)) >> 16;
  return (unsigned short)r;
}
__device__ __forceinline__ float b2f(unsigned short h) {
  union { unsigned int u; float f; } v; v.u = ((unsigned int)h) << 16;
  return v.f;
}
__device__ __forceinline__ unsigned fkey(float x) {
  unsigned k = __float_as_uint(x);
  return k ^ ((k & 0x80000000u) ? 0xFFFFFFFFu : 0x80000000u);
}
__device__ __forceinline__ float kdec(unsigned k) {
  k ^= (k & 0x80000000u) ? 0x80000000u : 0xFFFFFFFFu;
  return __uint_as_float(k);
}

// ---------------- one-shot init ----------------

__global__ void init_all_kernel(int* __restrict__ cntR, int* __restrict__ gcnt,
                                float* __restrict__ sums_all,
                                unsigned* __restrict__ pmaxk, unsigned* __restrict__ pmink,
                                float* __restrict__ psumg) {
  const int i = blockIdx.x * blockDim.x + threadIdx.x;
  if (i < NREP * N_NODES) cntR[i] = 0;
  if (i < N_GRAPH) gcnt[i] = 0;
  if (i < 2 * (128 + 256 + 384)) sums_all[i] = 0.f;
  if (i < POOL_TOT) { pmaxk[i] = 0u; pmink[i] = 0xFFFFFFFFu; psumg[i] = 0.f; }
}

// ---------------- CSR build (replicated histogram/cursor) ----------------

__global__ void hist_rep_kernel(const int* __restrict__ idx, int* __restrict__ cntR, int n) {
  int i = blockIdx.x * blockDim.x + threadIdx.x;
  if (i < n) {
    const int rep = blockIdx.x & (NREP - 1);
    atomicAdd(&cntR[rep * N_NODES + idx[i]], 1);
  }
}

// scan phase 1 fused with replica combine.
__global__ __launch_bounds__(256) void scan1_fused_kernel(int* __restrict__ cntR,
                                                          int* __restrict__ out,
                                                          int* __restrict__ part, int n) {
  __shared__ int sm[256];
  const int t = threadIdx.x;
  const int base = blockIdx.x * 1024 + t * 4;
  int v[4] = {0, 0, 0, 0};
#pragma unroll
  for (int j = 0; j < 4; ++j) {
    const int d = base + j;
    if (d < n) {
      int s = 0;
#pragma unroll
      for (int r = 0; r < NREP; ++r) {
        const int c = cntR[r * N_NODES + d];
        cntR[r * N_NODES + d] = s;
        s += c;
      }
      v[j] = s;
    }
  }
  const int tsum = v[0] + v[1] + v[2] + v[3];
  sm[t] = tsum;
  __syncthreads();
  for (int off = 1; off < 256; off <<= 1) {
    int x = (t >= off) ? sm[t - off] : 0;
    __syncthreads();
    sm[t] += x;
    __syncthreads();
  }
  const int excl = sm[t] - tsum;
  if (base     < n) out[base]     = excl;
  if (base + 1 < n) out[base + 1] = excl + v[0];
  if (base + 2 < n) out[base + 2] = excl + v[0] + v[1];
  if (base + 3 < n) out[base + 3] = excl + v[0] + v[1] + v[2];
  if (t == 255) part[blockIdx.x] = sm[255];
}

__global__ __launch_bounds__(256) void scan2_kernel(int* __restrict__ part, int nb,
                                                    int* __restrict__ total_out) {
  __shared__ int sm[256];
  const int t = threadIdx.x;
  const int v = (t < nb) ? part[t] : 0;
  sm[t] = v;
  __syncthreads();
  for (int off = 1; off < 256; off <<= 1) {
    int x = (t >= off) ? sm[t - off] : 0;
    __syncthreads();
    sm[t] += x;
    __syncthreads();
  }
  if (t < nb) part[t] = sm[t] - v;
  if (t == 255) *total_out = sm[255];
}

__global__ void scan3_cursor_kernel(int* __restrict__ out, const int* __restrict__ part,
                                    int* __restrict__ cntR, int n) {
  int i = blockIdx.x * blockDim.x + threadIdx.x;
  if (i >= n) return;
  const int rp = out[i] + part[i >> 10];
  out[i] = rp;
#pragma unroll
  for (int r = 0; r < NREP; ++r) cntR[r * N_NODES + i] += rp;
}

__global__ void bucket_kernel(const int* __restrict__ src, const int* __restrict__ dst,
                              const float* __restrict__ ew, int* __restrict__ cntR,
                              ull* __restrict__ epack, int E) {
  int e = blockIdx.x * blockDim.x + threadIdx.x;
  if (e < E) {
    const int rep = blockIdx.x & (NREP - 1);
    const int d = dst[e];
    const int p = atomicAdd(&cntR[rep * N_NODES + d], 1);
    epack[p] = ((ull)__float_as_uint(ew[e]) << 32) | (unsigned)src[e];
  }
}

__global__ __launch_bounds__(256) void hist_batch_kernel(const int* __restrict__ idx,
                                                         int* __restrict__ cnt, int n) {
  __shared__ int lh[N_GRAPH];
  lh[threadIdx.x] = 0;
  __syncthreads();
  int i = blockIdx.x * blockDim.x + threadIdx.x;
  if (i < n) atomicAdd(&lh[idx[i]], 1);
  __syncthreads();
  const int v = lh[threadIdx.x];
  if (v) atomicAdd(&cnt[threadIdx.x], v);
}

__global__ __launch_bounds__(256) void scan256_kernel(const int* __restrict__ cnt,
                                                      int* __restrict__ gptr) {
  __shared__ int sm[256];
  const int t = threadIdx.x;
  const int v = cnt[t];
  sm[t] = v;
  __syncthreads();
  for (int off = 1; off < 256; off <<= 1) {
    int x = (t >= off) ? sm[t - off] : 0;
    __syncthreads();
    sm[t] += x;
    __syncthreads();
  }
  gptr[t] = sm[t] - v;
  if (t == 255) gptr[256] = sm[255];
}

// ---------------- prep ----------------

__global__ void cast_bf16_kernel(const float* __restrict__ in,
                                 unsigned short* __restrict__ out, int npair) {
  int i = blockIdx.x * blockDim.x + threadIdx.x;
  if (i >= npair) return;
  float2 v = *(const float2*)(in + 2 * (size_t)i);
  ((unsigned int*)out)[i] = (unsigned int)f2b(v.x) | ((unsigned int)f2b(v.y) << 16);
}

__global__ __launch_bounds__(256) void wt_build_kernel(
    const float* __restrict__ wrel, const float* __restrict__ wroot,
    const float* __restrict__ brel, const float* __restrict__ sums_prev,
    const float* __restrict__ gamma_prev, const float* __restrict__ beta_prev,
    unsigned short* __restrict__ wt, float* __restrict__ u, float* __restrict__ v,
    int K, int N) {
  __shared__ float redu[256];
  __shared__ float redv[256];
  const int n = blockIdx.x;
  const int K2 = 2 * K;
  const float inv_n = 1.f / (float)N_NODES;
  float us = 0.f, vs = 0.f;
  for (int k = threadIdx.x; k < K2; k += 256) {
    const int kk = (k < K) ? k : k - K;
    const float w = (k < K) ? wrel[(size_t)kk * N + n] : wroot[(size_t)kk * N + n];
    float sc = 1.f, sh = 0.f;
    if (sums_prev) {
      const float mu  = sums_prev[kk] * inv_n;
      const float var = sums_prev[K + kk] * inv_n - mu * mu;
      sc = rsqrtf(var + BN_EPS) * gamma_prev[kk];
      sh = beta_prev[kk] - mu * sc;
    }
    wt[(size_t)n * K2 + k] = f2b(w * sc);
    if (k < K) us += sh * w; else vs += sh * w;
  }
  redu[threadIdx.x] = us; redv[threadIdx.x] = vs;
  __syncthreads();
  for (int o = 128; o > 0; o >>= 1) {
    if (threadIdx.x < o) {
      redu[threadIdx.x] += redu[threadIdx.x + o];
      redv[threadIdx.x] += redv[threadIdx.x + o];
    }
    __syncthreads();
  }
  if (threadIdx.x == 0) { u[n] = redu[0]; v[n] = brel[n] + redv[0]; }
}

// ---------------- aggregation: MLP-maximized gather (at its pattern roofline) --------

template <int D>
__global__ void agg_bf16_kernel(const unsigned short* __restrict__ h,
                                const int* __restrict__ rowptr,
                                const ull* __restrict__ epack,
                                unsigned short* __restrict__ agg,
                                float* __restrict__ degw_out) {
  int gid  = blockIdx.x * blockDim.x + threadIdx.x;
  int node = gid >> 6;
  int lane = threadIdx.x & 63;
  if (node >= N_NODES) return;
  const int beg = rowptr[node], end = rowptr[node + 1];
  constexpr int NP = D / 128;
  float acc0[NP], acc1[NP];
#pragma unroll
  for (int i = 0; i < NP; ++i) { acc0[i] = 0.f; acc1[i] = 0.f; }
  float wsum = 0.f;

  for (int c0 = beg; c0 < end; c0 += 64) {
    const int cn = min(64, end - c0);
    ull pk = 0;  // pad: src=0, w=0
    if (lane < cn) pk = epack[c0 + lane];
    const int   su = (int)(unsigned)pk;
    const float wf = __uint_as_float((unsigned)(pk >> 32));
    const int ng = (cn + 7) >> 3;  // groups of 8, padded
    for (int g = 0; g < ng; ++g) {
      int ss[8]; float wv[8];
#pragma unroll
      for (int j = 0; j < 8; ++j) {
        ss[j] = __shfl(su, g * 8 + j);
        wv[j] = __shfl(wf, g * 8 + j);
      }
      unsigned uu[8][NP];
#pragma unroll
      for (int j = 0; j < 8; ++j) {
        const unsigned int* row = (const unsigned int*)(h + (size_t)ss[j] * D);
#pragma unroll
        for (int i = 0; i < NP; ++i) uu[j][i] = row[lane + 64 * i];
      }
#pragma unroll
      for (int j = 0; j < 8; ++j) {
        wsum += wv[j];
#pragma unroll
        for (int i = 0; i < NP; ++i) {
          acc0[i] += b2f((unsigned short)(uu[j][i] & 0xFFFF)) * wv[j];
          acc1[i] += b2f((unsigned short)(uu[j][i] >> 16)) * wv[j];
        }
      }
    }
  }

  unsigned int* o = (unsigned int*)(agg + (size_t)node * D);
#pragma unroll
  for (int i = 0; i < NP; ++i)
    o[lane + 64 * i] = (unsigned int)f2b(acc0[i]) | ((unsigned int)f2b(acc1[i]) << 16);
  if (degw_out != nullptr && lane == 0) degw_out[node] = wsum;
}

// ---------------- MFMA GEMM with SINGLE-PASS fused pooling ----------------
// (round-7 verified best: gemm3 66.8us, total 495.2us. Round-8's direct-register
// variant was falsified — per-lane scattered fragment loads serialized at L1/L2 and
// doubled WRITE_SIZE; LDS staging is the traffic aggregator here, not overhead.)
// Structure: 3-buffer rotating LDS pipeline, raw s_barrier + counted vmcnt(4),
// global_load_lds, XCD-affine tiles, BK=32. Pooling accumulates in 24 registers
// during the single-pass epilogue (gslot as predicate, compile-time indices),
// shfl-reduced over lq, stored NON-atomically to partials privatized by
// (m_tile, n_tile, gslot, wave-half). Cold fallback (block spanning >2 graphs;
// impossible at ~195 rows/graph) uses global atomics on the old pmaxk arrays.

__global__ __launch_bounds__(256) void gemm_mfma_kernel(
    const unsigned short* __restrict__ Aagg, const unsigned short* __restrict__ Ah,
    const unsigned short* __restrict__ Wt,
    const float* __restrict__ u, const float* __restrict__ v,
    const float* __restrict__ degw, const int* __restrict__ batch,
    unsigned short* __restrict__ outH, float* __restrict__ sums,
    unsigned* __restrict__ pmaxk, unsigned* __restrict__ pmink,
    float* __restrict__ psumg,
    float* __restrict__ ppmax, float* __restrict__ ppmin, float* __restrict__ ppsum,
    int M, int K, int N) {
  __shared__ unsigned short As[3][128 * 32];
  __shared__ unsigned short Bs[3][128 * 32];
  __shared__ float col_s[256];
  __shared__ float dws[128];
  __shared__ int gbs[128];

  const int NT = N >> 7;
  const int id = blockIdx.x;
  const int xcd = id & 7;
  const int q   = id >> 3;
  const int m_tile = (q / NT) * 8 + xcd;
  if (m_tile >= MB_TILES) return;
  const int m0 = m_tile * 128;
  const int nt2 = q % NT;
  const int n0 = nt2 * 128;

  const int t  = threadIdx.x;
  const int lane = t & 63;
  const int w    = t >> 6;
  const int wm   = (w & 1) * 64;
  const int wn   = (w >> 1) * 64;
  const int l16  = lane & 15;
  const int lq   = lane >> 4;
  const int K2   = 2 * K;

  const int lrow  = lane >> 2;
  const int lslot = lane & 3;

  col_s[t] = 0.f;
  if (t < 128) {
    const int m = m0 + t;
    dws[t] = (m < M) ? degw[m] : 0.f;
    gbs[t] = (m < M) ? batch[m] : -1;
  }

  floatx4 acc[4][4];
#pragma unroll
  for (int i = 0; i < 4; ++i)
#pragma unroll
    for (int j = 0; j < 4; ++j) acc[i][j] = (floatx4){0.f, 0.f, 0.f, 0.f};

  // stage one 128x32 A-tile + B-tile into LDS buffers for K-offset k0.
  auto stage = [&](unsigned short* Ab, unsigned short* Bb, int k0) {
    const unsigned short* Asrc;
    int kbase;
    if (k0 < K) { Asrc = Aagg; kbase = k0; } else { Asrc = Ah; kbase = k0 - K; }
#pragma unroll
    for (int qq = 0; qq < 2; ++qq) {
      const int row = w * 32 + qq * 16 + lrow;
      const int gc  = (lslot ^ ((row >> 1) & 3)) * 8;
      const unsigned short* gA = Asrc + (size_t)(m0 + row) * K + kbase + gc;
      const unsigned short* gB = Wt + (size_t)(n0 + row) * K2 + k0 + gc;
      __builtin_amdgcn_global_load_lds((gas_ptr)gA, (las_ptr)(Ab + (w * 32 + qq * 16) * 32),
                                       16, 0, 0);
      __builtin_amdgcn_global_load_lds((gas_ptr)gB, (las_ptr)(Bb + (w * 32 + qq * 16) * 32),
                                       16, 0, 0);
    }
  };

  // ds_read fragments from buffer and run the 4x4 MFMA block (setprio'd).
  auto compute = [&](const unsigned short* Ab, const unsigned short* Bb) {
    short8 af[4], bfr[4];
#pragma unroll
    for (int i = 0; i < 4; ++i) {
      const int r = wm + i * 16 + l16;
      af[i] = *(const short8*)(Ab + r * 32 + (lq ^ ((r >> 1) & 3)) * 8);
    }
#pragma unroll
    for (int j = 0; j < 4; ++j) {
      const int r = wn + j * 16 + l16;
      bfr[j] = *(const short8*)(Bb + r * 32 + (lq ^ ((r >> 1) & 3)) * 8);
    }
    __builtin_amdgcn_s_setprio(1);
#pragma unroll
    for (int i = 0; i < 4; ++i)
#pragma unroll
      for (int j = 0; j < 4; ++j)
        acc[i][j] = __builtin_amdgcn_mfma_f32_16x16x32_bf16(af[i], bfr[j], acc[i][j], 0, 0, 0);
    __builtin_amdgcn_s_setprio(0);
  };

  const int NSTEP = K2 >> 5;  // 8 or 16

  unsigned short *A0 = &As[0][0], *A1 = &As[1][0], *A2 = &As[2][0];
  unsigned short *B0 = &Bs[0][0], *B1 = &Bs[1][0], *B2 = &Bs[2][0];

  stage(A0, B0, 0);        // 4 loads
  stage(A1, B1, 1 << 5);   // 8 outstanding

  for (int s = 0; s < NSTEP - 1; ++s) {
    asm volatile("s_waitcnt vmcnt(4)" ::: "memory");
    __builtin_amdgcn_s_barrier();           // step-s loads landed for all waves;
    __builtin_amdgcn_sched_barrier(0);      // also WAR fence for buf (s+2)%3
    if (s + 2 < NSTEP) stage(A2, B2, (s + 2) << 5);
    compute(A0, B0);
    unsigned short* tA = A0; A0 = A1; A1 = A2; A2 = tA;
    unsigned short* tB = B0; B0 = B1; B1 = B2; B2 = tB;
  }
  asm volatile("s_waitcnt vmcnt(0)" ::: "memory");
  __builtin_amdgcn_s_barrier();
  __builtin_amdgcn_sched_barrier(0);
  compute(A0, B0);

  float uu[4], vv[4];
#pragma unroll
  for (int j = 0; j < 4; ++j) {
    const int n = n0 + wn + j * 16 + l16;
    uu[j] = u[n]; vv[j] = v[n];
  }

  // ---- single-pass epilogue: activation + hp write + BN sums + register pooling ----
  const bool wout = (outH != nullptr);
  const int lastr = min(127, M - 1 - m0);
  const int gmin = gbs[0];
  const int gmax = gbs[lastr];

  float ts[4]  = {0.f, 0.f, 0.f, 0.f};
  float tss[4] = {0.f, 0.f, 0.f, 0.f};
  float px0[4], pn0[4], ps0[4], px1[4], pn1[4], ps1[4];
#pragma unroll
  for (int j = 0; j < 4; ++j) {
    px0[j] = FNEG; pn0[j] = FPOS; ps0[j] = 0.f;
    px1[j] = FNEG; pn1[j] = FPOS; ps1[j] = 0.f;
  }

#pragma unroll
  for (int i = 0; i < 4; ++i) {
    const int lrow2 = wm + i * 16 + lq * 4;
#pragma unroll
    for (int r = 0; r < 4; ++r) {
      const int row = lrow2 + r;
      const bool live = (m0 + row < M);
      const int gv = gbs[row];
      const float dwr = dws[row];
      const bool in0 = live && (gv == gmin);
      const bool in1 = live && (gmax != gmin) && (gv == gmax);
#pragma unroll
      for (int j = 0; j < 4; ++j) {
        const int n = n0 + wn + j * 16 + l16;
        float val = acc[i][j][r] + vv[j] + dwr * uu[j];
        val = val > 0.f ? val : LEAKY * val;
        acc[i][j][r] = val;
        if (live) {
          if (wout) outH[(size_t)(m0 + row) * N + n] = f2b(val);
          ts[j]  += val;
          tss[j] += val * val;
        }
        if (in0) { px0[j] = fmaxf(px0[j], val); pn0[j] = fminf(pn0[j], val); ps0[j] += val; }
        if (in1) { px1[j] = fmaxf(px1[j], val); pn1[j] = fminf(pn1[j], val); ps1[j] += val; }
      }
    }
  }

  const int half = w & 1;
#pragma unroll
  for (int j = 0; j < 4; ++j) {
    float a = ts[j], b = tss[j];
    a += __shfl_xor(a, 16); a += __shfl_xor(a, 32);
    b += __shfl_xor(b, 16); b += __shfl_xor(b, 32);
    float x0 = px0[j], n0v = pn0[j], s0v = ps0[j];
    x0 = fmaxf(x0, __shfl_xor(x0, 16)); x0 = fmaxf(x0, __shfl_xor(x0, 32));
    n0v = fminf(n0v, __shfl_xor(n0v, 16)); n0v = fminf(n0v, __shfl_xor(n0v, 32));
    s0v += __shfl_xor(s0v, 16); s0v += __shfl_xor(s0v, 32);
    float x1 = px1[j], n1v = pn1[j], s1v = ps1[j];
    x1 = fmaxf(x1, __shfl_xor(x1, 16)); x1 = fmaxf(x1, __shfl_xor(x1, 32));
    n1v = fminf(n1v, __shfl_xor(n1v, 16)); n1v = fminf(n1v, __shfl_xor(n1v, 32));
    s1v += __shfl_xor(s1v, 16); s1v += __shfl_xor(s1v, 32);
    if (lq == 0) {
      const int ci = wn + j * 16 + l16;
      atomicAdd(&col_s[ci], a);
      atomicAdd(&col_s[128 + ci], b);
      const size_t tb = (size_t)(m_tile * NT + nt2) * 2;
      const size_t sb0 = ((tb + 0) * 2 + half) * 128 + ci;
      const size_t sb1 = ((tb + 1) * 2 + half) * 128 + ci;
      ppmax[sb0] = x0;  ppmin[sb0] = n0v; ppsum[sb0] = s0v;
      ppmax[sb1] = x1;  ppmin[sb1] = n1v; ppsum[sb1] = s1v;
    }
  }

  // cold fallback: block spans >2 graphs (never for ~195-row graphs) -> global atomics
  if (gmax > gmin + 1) {
    for (int g = gmin + 1; g < gmax; ++g) {
#pragma unroll
      for (int j = 0; j < 4; ++j) {
        float mx = FNEG, mn = FPOS, sm = 0.f;
#pragma unroll
        for (int i = 0; i < 4; ++i) {
          const int lrow2 = wm + i * 16 + lq * 4;
#pragma unroll
          for (int r = 0; r < 4; ++r) {
            const int row = lrow2 + r;
            if (m0 + row < M && gbs[row] == g) {
              const float val = acc[i][j][r];
              mx = fmaxf(mx, val); mn = fminf(mn, val); sm += val;
            }
          }
        }
        mx = fmaxf(mx, __shfl_xor(mx, 16)); mx = fmaxf(mx, __shfl_xor(mx, 32));
        mn = fminf(mn, __shfl_xor(mn, 16)); mn = fminf(mn, __shfl_xor(mn, 32));
        sm += __shfl_xor(sm, 16); sm += __shfl_xor(sm, 32);
        if (lq == 0 && mx > -3.3e38f) {
          const size_t pi = (size_t)g * N + (n0 + wn + j * 16 + l16);
          atomicMax(&pmaxk[pi], fkey(mx));
          atomicMin(&pmink[pi], fkey(mn));
          atomicAdd(&psumg[pi], sm);
        }
      }
    }
  }

  __syncthreads();
  if (t < 128) {
    atomicAdd(&sums[n0 + t], col_s[t]);
    atomicAdd(&sums[N + n0 + t], col_s[128 + t]);
  }
}

// ---------------- combined pool finalize: merge privatized partials + fallback ----------

__global__ void pool_finalize_all_kernel(const unsigned* __restrict__ pmaxk,
                                         const unsigned* __restrict__ pmink,
                                         const float* __restrict__ psumg,
                                         const float* __restrict__ ppmax,
                                         const float* __restrict__ ppmin,
                                         const float* __restrict__ ppsum,
                                         const float* __restrict__ sums_all,
                                         const float* __restrict__ gamma1, const float* __restrict__ beta1,
                                         const float* __restrict__ gamma2, const float* __restrict__ beta2,
                                         const float* __restrict__ gamma3, const float* __restrict__ beta3,
                                         const int* __restrict__ gptr,
                                         const int* __restrict__ batch,
                                         float* __restrict__ z) {
  int i = blockIdx.x * blockDim.x + threadIdx.x;
  if (i >= POOL_TOT) return;
  int C, zoff, li, NTL;
  size_t ppo;
  const float *sums, *gamma, *beta;
  if (i < N_GRAPH * 128) {
    C = 128; zoff = 0; li = i; NTL = 1; ppo = 0;
    sums = sums_all; gamma = gamma1; beta = beta1;
  } else if (i < N_GRAPH * (128 + 256)) {
    C = 256; zoff = 384; li = i - N_GRAPH * 128; NTL = 2; ppo = PP_L1;
    sums = sums_all + 2 * 128; gamma = gamma2; beta = beta2;
  } else {
    C = 384; zoff = 1152; li = i - N_GRAPH * (128 + 256); NTL = 3; ppo = PP_L1 + PP_L2;
    sums = sums_all + 2 * (128 + 256); gamma = gamma3; beta = beta3;
  }
  const int g = li / C, c = li % C;
  const int cnt = gptr[g + 1] - gptr[g];

  // merge fallback atomics (neutral unless a block spanned >2 graphs)
  float mx = FNEG, mn = FPOS, sm = psumg[i];
  {
    const unsigned pk = pmaxk[i];
    if (pk != 0u) mx = kdec(pk);
    const unsigned nk = pmink[i];
    if (nk != 0xFFFFFFFFu) mn = kdec(nk);
  }
  // merge privatized per-(m_tile, gslot, half) partials
  if (cnt > 0) {
    const int mt_lo = gptr[g] >> 7;
    const int mt_hi = (gptr[g + 1] - 1) >> 7;
    const int nt = c >> 7, cc = c & 127;
    for (int mt = mt_lo; mt <= mt_hi; ++mt) {
      const int g0 = batch[mt << 7];
      int grel = (g == g0) ? 0 : -1;
      if (grel < 0) {
        const int lastm = min((mt << 7) + 127, N_NODES - 1);
        if (g == batch[lastm]) grel = 1;
      }
      if (grel >= 0) {
        const size_t b0 = ppo + (((size_t)(mt * NTL + nt) * 2 + grel) * 2 + 0) * 128 + cc;
        const size_t b1 = b0 + 128;
        mx = fmaxf(mx, fmaxf(ppmax[b0], ppmax[b1]));
        mn = fminf(mn, fminf(ppmin[b0], ppmin[b1]));
        sm += ppsum[b0] + ppsum[b1];
      }
    }
  }

  const float inv_n = 1.f / (float)N_NODES;
  const float mu  = sums[c] * inv_n;
  const float var = sums[C + c] * inv_n - mu * mu;
  const float sc  = rsqrtf(var + BN_EPS) * gamma[c];
  const float sh  = beta[c] - mu * sc;
  const float zmax = (sc >= 0.f ? mx : mn) * sc + sh;
  const float zsum = sm * sc + (float)cnt * sh;
  float* zg = z + (size_t)g * Z_DIM + zoff;
  zg[c]         = (cnt > 0) ? zmax : 0.f;
  zg[C + c]     = zsum / (float)(cnt > 0 ? cnt : 1);
  zg[2 * C + c] = zsum;
}

// ---------------- FC head ----------------

__global__ __launch_bounds__(1024) void fc_kernel(const float* __restrict__ z,
                                                  const float* __restrict__ w1, const float* __restrict__ b1,
                                                  const float* __restrict__ w2, const float* __restrict__ b2,
                                                  const float* __restrict__ w3, const float* __restrict__ b3,
                                                  float* __restrict__ out) {
  __shared__ float zs[Z_DIM];
  __shared__ float part[8][128];
  __shared__ float h1s[128];
  __shared__ float red[128][2];
  __shared__ float y2[2];
  const int g  = blockIdx.x;
  const int t  = threadIdx.x;
  const int c  = t & 127;
  const int ks = t >> 7;
  for (int i = t; i < Z_DIM; i += 1024) zs[i] = z[(size_t)g * Z_DIM + i];
  __syncthreads();

  constexpr int KCH = Z_DIM / 8;
  const int k0 = ks * KCH;
  float acc = 0.f;
#pragma unroll 4
  for (int k = k0; k < k0 + KCH; ++k) acc += zs[k] * w1[(size_t)k * 128 + c];
  part[ks][c] = acc;
  __syncthreads();

  if (t < 128) {
    float s = b1[t];
#pragma unroll
    for (int i = 0; i < 8; ++i) s += part[i][t];
    h1s[t] = fmaxf(s, 0.f);
  }
  __syncthreads();
  if (t < 128) {
    red[t][0] = h1s[t] * w2[t * 2 + 0];
    red[t][1] = h1s[t] * w2[t * 2 + 1];
  }
  __syncthreads();
  if (t < 2) {
    float s = b2[t];
    for (int k = 0; k < 128; ++k) s += red[k][t];
    y2[t] = fmaxf(s, 0.f);
  }
  __syncthreads();
  if (t == 0) {
    const float z0 = y2[0] * w3[0] + y2[1] * w3[2] + b3[0];
    const float z1 = y2[0] * w3[1] + y2[1] * w3[3] + b3[1];
    const float m  = fmaxf(z0, z1);
    const float lse = m + logf(expf(z0 - m) + expf(z1 - m));
    out[g * 2 + 0] = z0 - lse;
    out[g * 2 + 1] = z1 - lse;
  }
}

// ---------------- launch ----------------

extern "C" void kernel_launch(void* const* d_in, const int* in_sizes, int n_in,
                              void* d_out, int out_size, void* d_ws, size_t ws_size,
                              hipStream_t stream) {
  (void)in_sizes; (void)n_in; (void)out_size; (void)ws_size;
  const float* x        = (const float*)d_in[0];
  const int*   eidx     = (const int*)d_in[1];
  const int*   batch    = (const int*)d_in[2];
  const float* eattr    = (const float*)d_in[3];
  const float* w_rel1   = (const float*)d_in[4];
  const float* b_rel1   = (const float*)d_in[5];
  const float* w_root1  = (const float*)d_in[6];
  const float* w_rel2   = (const float*)d_in[7];
  const float* b_rel2   = (const float*)d_in[8];
  const float* w_root2  = (const float*)d_in[9];
  const float* w_rel3   = (const float*)d_in[10];
  const float* b_rel3   = (const float*)d_in[11];
  const float* w_root3  = (const float*)d_in[12];
  const float* gamma1   = (const float*)d_in[13];
  const float* beta1    = (const float*)d_in[14];
  const float* gamma2   = (const float*)d_in[15];
  const float* beta2    = (const float*)d_in[16];
  const float* gamma3   = (const float*)d_in[17];
  const float* beta3    = (const float*)d_in[18];
  const float* w_lin1   = (const float*)d_in[19];
  const float* b_lin1   = (const float*)d_in[20];
  const float* w_lin2   = (const float*)d_in[21];
  const float* b_lin2   = (const float*)d_in[22];
  const float* w_lin3   = (const float*)d_in[23];
  const float* b_lin3   = (const float*)d_in[24];

  const int* src = eidx;
  const int* dst = eidx + N_EDGES;
  float* outp = (float*)d_out;

  char* ws = (char*)d_ws;
  size_t off = 0;
  auto alloc = [&](size_t bytes) -> void* {
    void* p = ws + off;
    off += (bytes + 255) & ~(size_t)255;
    return p;
  };
  int*   rowptr = (int*)alloc((N_NODES + 1) * sizeof(int));
  int*   cntR   = (int*)alloc((size_t)NREP * N_NODES * sizeof(int));
  int*   gptr   = (int*)alloc((N_GRAPH + 1) * sizeof(int));
  int*   gcnt   = (int*)alloc(N_GRAPH * sizeof(int));
  int*   part   = (int*)alloc(256 * sizeof(int));
  ull*   epack  = (ull*)alloc((size_t)N_EDGES * sizeof(ull));
  float* degw   = (float*)alloc(N_NODES * sizeof(float));
  float* sums_all = (float*)alloc(2 * (128 + 256 + 384) * sizeof(float));
  float* zbuf   = (float*)alloc((size_t)N_GRAPH * Z_DIM * sizeof(float));
  unsigned* pmaxk = (unsigned*)alloc((size_t)POOL_TOT * 4);
  unsigned* pmink = (unsigned*)alloc((size_t)POOL_TOT * 4);
  float*    psumg = (float*)alloc((size_t)POOL_TOT * 4);
  float* ppmax = (float*)alloc((size_t)PP_TOT * 4);
  float* ppmin = (float*)alloc((size_t)PP_TOT * 4);
  float* ppsum = (float*)alloc((size_t)PP_TOT * 4);
  unsigned short* xb   = (unsigned short*)alloc((size_t)M_PAD * 128 * 2);
  unsigned short* hp1  = (unsigned short*)alloc((size_t)M_PAD * 128 * 2);
  unsigned short* hp2  = (unsigned short*)alloc((size_t)M_PAD * 256 * 2);
  unsigned short* aggb = (unsigned short*)alloc((size_t)M_PAD * 256 * 2);
  unsigned short* wt1 = (unsigned short*)alloc((size_t)128 * 256 * 2);
  unsigned short* wt2 = (unsigned short*)alloc((size_t)256 * 256 * 2);
  unsigned short* wt3 = (unsigned short*)alloc((size_t)384 * 512 * 2);
  float* u1 = (float*)alloc(128 * sizeof(float));
  float* v1 = (float*)alloc(128 * sizeof(float));
  float* u2 = (float*)alloc(256 * sizeof(float));
  float* v2 = (float*)alloc(256 * sizeof(float));
  float* u3 = (float*)alloc(384 * sizeof(float));
  float* v3 = (float*)alloc(384 * sizeof(float));

  float* sums1 = sums_all;
  float* sums2 = sums_all + 2 * 128;
  float* sums3 = sums_all + 2 * (128 + 256);
  const int PO1 = 0, PO2 = N_GRAPH * 128, PO3 = N_GRAPH * (128 + 256);

  const int EB = (N_EDGES + 255) / 256;
  const int NB = (N_NODES + 255) / 256;
  const int SB = (N_NODES + 1023) / 1024;

  init_all_kernel<<<(NREP * N_NODES + 255) / 256, 256, 0, stream>>>(
      cntR, gcnt, sums_all, pmaxk, pmink, psumg);

  // ---- CSR by dst ----
  hist_rep_kernel<<<EB, 256, 0, stream>>>(dst, cntR, N_EDGES);
  scan1_fused_kernel<<<SB, 256, 0, stream>>>(cntR, rowptr, part, N_NODES);
  scan2_kernel<<<1, 256, 0, stream>>>(part, SB, rowptr + N_NODES);
  scan3_cursor_kernel<<<NB, 256, 0, stream>>>(rowptr, part, cntR, N_NODES);
  bucket_kernel<<<EB, 256, 0, stream>>>(src, dst, eattr, cntR, epack, N_EDGES);

  // ---- graph segment pointers ----
  hist_batch_kernel<<<NB, 256, 0, stream>>>(batch, gcnt, N_NODES);
  scan256_kernel<<<1, 256, 0, stream>>>(gcnt, gptr);

  // ---- prep ----
  cast_bf16_kernel<<<(N_NODES * 128 / 2 + 255) / 256, 256, 0, stream>>>(x, xb, N_NODES * 128 / 2);
  wt_build_kernel<<<128, 256, 0, stream>>>(w_rel1, w_root1, b_rel1, nullptr, nullptr, nullptr,
                                           wt1, u1, v1, 128, 128);

  const int aggBlocks = (N_NODES * 64 + 255) / 256;

  // ---- layer 1: 128 -> 128 ----
  agg_bf16_kernel<128><<<aggBlocks, 256, 0, stream>>>(xb, rowptr, epack, aggb, degw);
  gemm_mfma_kernel<<<392 * 1, 256, 0, stream>>>(aggb, xb, wt1, u1, v1, degw, batch,
                                                hp1, sums1, pmaxk + PO1, pmink + PO1,
                                                psumg + PO1, ppmax, ppmin, ppsum,
                                                N_NODES, 128, 128);
  wt_build_kernel<<<256, 256, 0, stream>>>(w_rel2, w_root2, b_rel2, sums1, gamma1, beta1,
                                           wt2, u2, v2, 128, 256);

  // ---- layer 2: 128 -> 256 ----
  agg_bf16_kernel<128><<<aggBlocks, 256, 0, stream>>>(hp1, rowptr, epack, aggb, nullptr);
  gemm_mfma_kernel<<<392 * 2, 256, 0, stream>>>(aggb, hp1, wt2, u2, v2, degw, batch,
                                                hp2, sums2, pmaxk + PO2, pmink + PO2,
                                                psumg + PO2, ppmax + PP_L1, ppmin + PP_L1,
                                                ppsum + PP_L1, N_NODES, 128, 256);
  wt_build_kernel<<<384, 256, 0, stream>>>(w_rel3, w_root3, b_rel3, sums2, gamma2, beta2,
                                           wt3, u3, v3, 256, 384);

  // ---- layer 3: 256 -> 384 (no hp3 write: pooling fused, output unused) ----
  agg_bf16_kernel<256><<<aggBlocks, 256, 0, stream>>>(hp2, rowptr, epack, aggb, nullptr);
  gemm_mfma_kernel<<<392 * 3, 256, 0, stream>>>(aggb, hp2, wt3, u3, v3, degw, batch,
                                                (unsigned short*)nullptr, sums3,
                                                pmaxk + PO3, pmink + PO3, psumg + PO3,
                                                ppmax + PP_L1 + PP_L2, ppmin + PP_L1 + PP_L2,
                                                ppsum + PP_L1 + PP_L2, N_NODES, 256, 384);

  // ---- combined pool finalize (all layers) + FC head ----
  pool_finalize_all_kernel<<<(POOL_TOT + 255) / 256, 256, 0, stream>>>(
      pmaxk, pmink, psumg, ppmax, ppmin, ppsum, sums_all,
      gamma1, beta1, gamma2, beta2, gamma3, beta3, gptr, batch, zbuf);
  fc_kernel<<<N_GRAPH, 1024, 0, stream>>>(zbuf, w_lin1, b_lin1, w_lin2, b_lin2, w_lin3, b_lin3,
                                          outp);
}

// Round 10
// 499.659 us; speedup vs baseline: 1.1073x; 1.0211x over previous
//
#include <hip/hip_runtime.h>
#include <cstdint>
#include <cstddef>

#define N_NODES 50000
#define M_PAD   50048   // 391 * 128
#define MB_TILES 391
#define N_EDGES 800000
#define N_GRAPH 256
#define Z_DIM   2304
#define NREP    16
#define POOL_TOT (N_GRAPH * (128 + 256 + 384))
// privatized pooling partials: per (m_tile, n_tile, gslot{0,1}, half{0,1}) x 128 cols
#define PP_L1 (MB_TILES * 1 * 2 * 2 * 128)   // 200192
#define PP_L2 (MB_TILES * 2 * 2 * 2 * 128)   // 400384
#define PP_L3 (MB_TILES * 3 * 2 * 2 * 128)   // 600576
#define PP_TOT (PP_L1 + PP_L2 + PP_L3)

static constexpr float LEAKY  = 0.01f;
static constexpr float BN_EPS = 1e-5f;
static constexpr float FNEG   = -3.4e38f;
static constexpr float FPOS   =  3.4e38f;

typedef short short8 __attribute__((ext_vector_type(8)));
typedef float floatx4 __attribute__((ext_vector_type(4)));
typedef const __attribute__((address_space(1))) unsigned int* gas_ptr;
typedef __attribute__((address_space(3))) unsigned int* las_ptr;
typedef unsigned long long ull;

__device__ __forceinline__ unsigned short f2b(float f) {
  union { float f; unsigned int u; } v; v.f = f;
  unsigned int u = v.u;
  unsigned int r = (u + 0x7FFFu + ((u >> 16) & 1u)) >> 16;
  return (unsigned short)r;
}
__device__ __forceinline__ float b2f(unsigned short h) {
  union { unsigned int u; float f; } v; v.u = ((unsigned int)h) << 16;
  return v.f;
}
__device__ __forceinline__ unsigned fkey(float x) {
  unsigned k = __float_as_uint(x);
  return k ^ ((k & 0x80000000u) ? 0xFFFFFFFFu : 0x80000000u);
}
__device__ __forceinline__ float kdec(unsigned k) {
  k ^= (k & 0x80000000u) ? 0x80000000u : 0xFFFFFFFFu;
  return __uint_as_float(k);
}

// ---------------- one-shot init ----------------

__global__ void init_all_kernel(int* __restrict__ cntR, int* __restrict__ gcnt,
                                float* __restrict__ sums_all,
                                unsigned* __restrict__ pmaxk, unsigned* __restrict__ pmink,
                                float* __restrict__ psumg) {
  const int i = blockIdx.x * blockDim.x + threadIdx.x;
  if (i < NREP * N_NODES) cntR[i] = 0;
  if (i < N_GRAPH) gcnt[i] = 0;
  if (i < 2 * (128 + 256 + 384)) sums_all[i] = 0.f;
  if (i < POOL_TOT) { pmaxk[i] = 0u; pmink[i] = 0xFFFFFFFFu; psumg[i] = 0.f; }
}

// ---------------- CSR build (replicated histogram/cursor) ----------------

__global__ void hist_rep_kernel(const int* __restrict__ idx, int* __restrict__ cntR, int n) {
  int i = blockIdx.x * blockDim.x + threadIdx.x;
  if (i < n) {
    const int rep = blockIdx.x & (NREP - 1);
    atomicAdd(&cntR[rep * N_NODES + idx[i]], 1);
  }
}

// scan phase 1 fused with replica combine.
__global__ __launch_bounds__(256) void scan1_fused_kernel(int* __restrict__ cntR,
                                                          int* __restrict__ out,
                                                          int* __restrict__ part, int n) {
  __shared__ int sm[256];
  const int t = threadIdx.x;
  const int base = blockIdx.x * 1024 + t * 4;
  int v[4] = {0, 0, 0, 0};
#pragma unroll
  for (int j = 0; j < 4; ++j) {
    const int d = base + j;
    if (d < n) {
      int s = 0;
#pragma unroll
      for (int r = 0; r < NREP; ++r) {
        const int c = cntR[r * N_NODES + d];
        cntR[r * N_NODES + d] = s;
        s += c;
      }
      v[j] = s;
    }
  }
  const int tsum = v[0] + v[1] + v[2] + v[3];
  sm[t] = tsum;
  __syncthreads();
  for (int off = 1; off < 256; off <<= 1) {
    int x = (t >= off) ? sm[t - off] : 0;
    __syncthreads();
    sm[t] += x;
    __syncthreads();
  }
  const int excl = sm[t] - tsum;
  if (base     < n) out[base]     = excl;
  if (base + 1 < n) out[base + 1] = excl + v[0];
  if (base + 2 < n) out[base + 2] = excl + v[0] + v[1];
  if (base + 3 < n) out[base + 3] = excl + v[0] + v[1] + v[2];
  if (t == 255) part[blockIdx.x] = sm[255];
}

__global__ __launch_bounds__(256) void scan2_kernel(int* __restrict__ part, int nb,
                                                    int* __restrict__ total_out) {
  __shared__ int sm[256];
  const int t = threadIdx.x;
  const int v = (t < nb) ? part[t] : 0;
  sm[t] = v;
  __syncthreads();
  for (int off = 1; off < 256; off <<= 1) {
    int x = (t >= off) ? sm[t - off] : 0;
    __syncthreads();
    sm[t] += x;
    __syncthreads();
  }
  if (t < nb) part[t] = sm[t] - v;
  if (t == 255) *total_out = sm[255];
}

__global__ void scan3_cursor_kernel(int* __restrict__ out, const int* __restrict__ part,
                                    int* __restrict__ cntR, int n) {
  int i = blockIdx.x * blockDim.x + threadIdx.x;
  if (i >= n) return;
  const int rp = out[i] + part[i >> 10];
  out[i] = rp;
#pragma unroll
  for (int r = 0; r < NREP; ++r) cntR[r * N_NODES + i] += rp;
}

__global__ void bucket_kernel(const int* __restrict__ src, const int* __restrict__ dst,
                              const float* __restrict__ ew, int* __restrict__ cntR,
                              ull* __restrict__ epack, int E) {
  int e = blockIdx.x * blockDim.x + threadIdx.x;
  if (e < E) {
    const int rep = blockIdx.x & (NREP - 1);
    const int d = dst[e];
    const int p = atomicAdd(&cntR[rep * N_NODES + d], 1);
    epack[p] = ((ull)__float_as_uint(ew[e]) << 32) | (unsigned)src[e];
  }
}

__global__ __launch_bounds__(256) void hist_batch_kernel(const int* __restrict__ idx,
                                                         int* __restrict__ cnt, int n) {
  __shared__ int lh[N_GRAPH];
  lh[threadIdx.x] = 0;
  __syncthreads();
  int i = blockIdx.x * blockDim.x + threadIdx.x;
  if (i < n) atomicAdd(&lh[idx[i]], 1);
  __syncthreads();
  const int v = lh[threadIdx.x];
  if (v) atomicAdd(&cnt[threadIdx.x], v);
}

__global__ __launch_bounds__(256) void scan256_kernel(const int* __restrict__ cnt,
                                                      int* __restrict__ gptr) {
  __shared__ int sm[256];
  const int t = threadIdx.x;
  const int v = cnt[t];
  sm[t] = v;
  __syncthreads();
  for (int off = 1; off < 256; off <<= 1) {
    int x = (t >= off) ? sm[t - off] : 0;
    __syncthreads();
    sm[t] += x;
    __syncthreads();
  }
  gptr[t] = sm[t] - v;
  if (t == 255) gptr[256] = sm[255];
}

// ---------------- prep ----------------

__global__ void cast_bf16_kernel(const float* __restrict__ in,
                                 unsigned short* __restrict__ out, int npair) {
  int i = blockIdx.x * blockDim.x + threadIdx.x;
  if (i >= npair) return;
  float2 v = *(const float2*)(in + 2 * (size_t)i);
  ((unsigned int*)out)[i] = (unsigned int)f2b(v.x) | ((unsigned int)f2b(v.y) << 16);
}

__global__ __launch_bounds__(256) void wt_build_kernel(
    const float* __restrict__ wrel, const float* __restrict__ wroot,
    const float* __restrict__ brel, const float* __restrict__ sums_prev,
    const float* __restrict__ gamma_prev, const float* __restrict__ beta_prev,
    unsigned short* __restrict__ wt, float* __restrict__ u, float* __restrict__ v,
    int K, int N) {
  __shared__ float redu[256];
  __shared__ float redv[256];
  const int n = blockIdx.x;
  const int K2 = 2 * K;
  const float inv_n = 1.f / (float)N_NODES;
  float us = 0.f, vs = 0.f;
  for (int k = threadIdx.x; k < K2; k += 256) {
    const int kk = (k < K) ? k : k - K;
    const float w = (k < K) ? wrel[(size_t)kk * N + n] : wroot[(size_t)kk * N + n];
    float sc = 1.f, sh = 0.f;
    if (sums_prev) {
      const float mu  = sums_prev[kk] * inv_n;
      const float var = sums_prev[K + kk] * inv_n - mu * mu;
      sc = rsqrtf(var + BN_EPS) * gamma_prev[kk];
      sh = beta_prev[kk] - mu * sc;
    }
    wt[(size_t)n * K2 + k] = f2b(w * sc);
    if (k < K) us += sh * w; else vs += sh * w;
  }
  redu[threadIdx.x] = us; redv[threadIdx.x] = vs;
  __syncthreads();
  for (int o = 128; o > 0; o >>= 1) {
    if (threadIdx.x < o) {
      redu[threadIdx.x] += redu[threadIdx.x + o];
      redv[threadIdx.x] += redv[threadIdx.x + o];
    }
    __syncthreads();
  }
  if (threadIdx.x == 0) { u[n] = redu[0]; v[n] = brel[n] + redv[0]; }
}

// ---------------- aggregation: MLP-maximized gather (at its pattern roofline) --------

template <int D>
__global__ void agg_bf16_kernel(const unsigned short* __restrict__ h,
                                const int* __restrict__ rowptr,
                                const ull* __restrict__ epack,
                                unsigned short* __restrict__ agg,
                                float* __restrict__ degw_out) {
  int gid  = blockIdx.x * blockDim.x + threadIdx.x;
  int node = gid >> 6;
  int lane = threadIdx.x & 63;
  if (node >= N_NODES) return;
  const int beg = rowptr[node], end = rowptr[node + 1];
  constexpr int NP = D / 128;
  float acc0[NP], acc1[NP];
#pragma unroll
  for (int i = 0; i < NP; ++i) { acc0[i] = 0.f; acc1[i] = 0.f; }
  float wsum = 0.f;

  for (int c0 = beg; c0 < end; c0 += 64) {
    const int cn = min(64, end - c0);
    ull pk = 0;  // pad: src=0, w=0
    if (lane < cn) pk = epack[c0 + lane];
    const int   su = (int)(unsigned)pk;
    const float wf = __uint_as_float((unsigned)(pk >> 32));
    const int ng = (cn + 7) >> 3;  // groups of 8, padded
    for (int g = 0; g < ng; ++g) {
      int ss[8]; float wv[8];
#pragma unroll
      for (int j = 0; j < 8; ++j) {
        ss[j] = __shfl(su, g * 8 + j);
        wv[j] = __shfl(wf, g * 8 + j);
      }
      unsigned uu[8][NP];
#pragma unroll
      for (int j = 0; j < 8; ++j) {
        const unsigned int* row = (const unsigned int*)(h + (size_t)ss[j] * D);
#pragma unroll
        for (int i = 0; i < NP; ++i) uu[j][i] = row[lane + 64 * i];
      }
#pragma unroll
      for (int j = 0; j < 8; ++j) {
        wsum += wv[j];
#pragma unroll
        for (int i = 0; i < NP; ++i) {
          acc0[i] += b2f((unsigned short)(uu[j][i] & 0xFFFF)) * wv[j];
          acc1[i] += b2f((unsigned short)(uu[j][i] >> 16)) * wv[j];
        }
      }
    }
  }

  unsigned int* o = (unsigned int*)(agg + (size_t)node * D);
#pragma unroll
  for (int i = 0; i < NP; ++i)
    o[lane + 64 * i] = (unsigned int)f2b(acc0[i]) | ((unsigned int)f2b(acc1[i]) << 16);
  if (degw_out != nullptr && lane == 0) degw_out[node] = wsum;
}

// ---------------- MFMA GEMM with SINGLE-PASS fused pooling ----------------
// Round-10 change vs round-7 (verified best): LDS 51.2KB -> 40.0KB to lift residency
// 3 -> 4 blocks/CU. (a) B is double-buffered (Wt is small + reused by all blocks ->
// L2-hot, ~200cy latency, distance-1 prefetch suffices); A stays triple-buffered
// (Aagg/Ah panels, L2/L3 latency, needs distance 2 — r1-vs-r2 evidence). Per-iter
// issue order: [vmcnt(2); barrier; stage_B(s+1); stage_A(s+2); compute(s)] — the
// single vmcnt(2) leaves exactly A(s+1)'s 2 loads in flight, so A(s),B(s) have
// landed. WAR safe: both stages are issued after the iter-s barrier, targets were
// last read in compute(s-1) which all waves finish before that barrier (same
// discipline as validated 3-buffer rotation). (b) col_s/dws/gbs alias the A-buffer
// space (dead after the K-loop) and are initialized in the epilogue behind a
// barrier. Epilogue register pooling unchanged (validated r7).

__global__ __launch_bounds__(256) void gemm_mfma_kernel(
    const unsigned short* __restrict__ Aagg, const unsigned short* __restrict__ Ah,
    const unsigned short* __restrict__ Wt,
    const float* __restrict__ u, const float* __restrict__ v,
    const float* __restrict__ degw, const int* __restrict__ batch,
    unsigned short* __restrict__ outH, float* __restrict__ sums,
    unsigned* __restrict__ pmaxk, unsigned* __restrict__ pmink,
    float* __restrict__ psumg,
    float* __restrict__ ppmax, float* __restrict__ ppmin, float* __restrict__ ppsum,
    int M, int K, int N) {
  __shared__ char smem[40960];                                  // 24K A + 16K B
  unsigned short* AsBase = (unsigned short*)smem;               // 3 x 4096 shorts
  unsigned short* BsBase = (unsigned short*)(smem + 24576);     // 2 x 4096 shorts
  float* col_s = (float*)smem;            // epilogue-only, aliases As[0]
  float* dws   = (float*)(smem + 1024);   // epilogue-only
  int*   gbs   = (int*)(smem + 1536);     // epilogue-only

  const int NT = N >> 7;
  const int id = blockIdx.x;
  const int xcd = id & 7;
  const int q   = id >> 3;
  const int m_tile = (q / NT) * 8 + xcd;
  if (m_tile >= MB_TILES) return;
  const int m0 = m_tile * 128;
  const int nt2 = q % NT;
  const int n0 = nt2 * 128;

  const int t  = threadIdx.x;
  const int lane = t & 63;
  const int w    = t >> 6;
  const int wm   = (w & 1) * 64;
  const int wn   = (w >> 1) * 64;
  const int l16  = lane & 15;
  const int lq   = lane >> 4;
  const int K2   = 2 * K;

  const int lrow  = lane >> 2;
  const int lslot = lane & 3;

  floatx4 acc[4][4];
#pragma unroll
  for (int i = 0; i < 4; ++i)
#pragma unroll
    for (int j = 0; j < 4; ++j) acc[i][j] = (floatx4){0.f, 0.f, 0.f, 0.f};

  // stage one 128x32 A-tile (2 gload_lds/thread) for K-offset k0.
  auto stage_A = [&](unsigned short* Ab, int k0) {
    const unsigned short* Asrc;
    int kbase;
    if (k0 < K) { Asrc = Aagg; kbase = k0; } else { Asrc = Ah; kbase = k0 - K; }
#pragma unroll
    for (int qq = 0; qq < 2; ++qq) {
      const int row = w * 32 + qq * 16 + lrow;
      const int gc  = (lslot ^ ((row >> 1) & 3)) * 8;
      const unsigned short* gA = Asrc + (size_t)(m0 + row) * K + kbase + gc;
      __builtin_amdgcn_global_load_lds((gas_ptr)gA, (las_ptr)(Ab + (w * 32 + qq * 16) * 32),
                                       16, 0, 0);
    }
  };
  // stage one 128x32 B-tile (2 gload_lds/thread) for K-offset k0.
  auto stage_B = [&](unsigned short* Bb, int k0) {
#pragma unroll
    for (int qq = 0; qq < 2; ++qq) {
      const int row = w * 32 + qq * 16 + lrow;
      const int gc  = (lslot ^ ((row >> 1) & 3)) * 8;
      const unsigned short* gB = Wt + (size_t)(n0 + row) * K2 + k0 + gc;
      __builtin_amdgcn_global_load_lds((gas_ptr)gB, (las_ptr)(Bb + (w * 32 + qq * 16) * 32),
                                       16, 0, 0);
    }
  };

  // ds_read fragments from buffer and run the 4x4 MFMA block (setprio'd).
  auto compute = [&](const unsigned short* Ab, const unsigned short* Bb) {
    short8 af[4], bfr[4];
#pragma unroll
    for (int i = 0; i < 4; ++i) {
      const int r = wm + i * 16 + l16;
      af[i] = *(const short8*)(Ab + r * 32 + (lq ^ ((r >> 1) & 3)) * 8);
    }
#pragma unroll
    for (int j = 0; j < 4; ++j) {
      const int r = wn + j * 16 + l16;
      bfr[j] = *(const short8*)(Bb + r * 32 + (lq ^ ((r >> 1) & 3)) * 8);
    }
    __builtin_amdgcn_s_setprio(1);
#pragma unroll
    for (int i = 0; i < 4; ++i)
#pragma unroll
      for (int j = 0; j < 4; ++j)
        acc[i][j] = __builtin_amdgcn_mfma_f32_16x16x32_bf16(af[i], bfr[j], acc[i][j], 0, 0, 0);
    __builtin_amdgcn_s_setprio(0);
  };

  const int NSTEP = K2 >> 5;  // 8 or 16

  unsigned short *A0 = AsBase, *A1 = AsBase + 4096, *A2 = AsBase + 8192;
  unsigned short *B0 = BsBase, *B1 = BsBase + 4096;

  // prologue mimics steady-state issue order: A(0), B(0), A(1) -> 6 loads out
  stage_A(A0, 0);
  stage_B(B0, 0);
  stage_A(A1, 1 << 5);

  for (int s = 0; s < NSTEP - 1; ++s) {
    // wait until only the 2 newest (A(s+1)) remain -> A(s), B(s) landed
    asm volatile("s_waitcnt vmcnt(2)" ::: "memory");
    __builtin_amdgcn_s_barrier();
    __builtin_amdgcn_sched_barrier(0);
    stage_B(B1, (s + 1) << 5);                 // s+1 < NSTEP inside loop
    if (s + 2 < NSTEP) stage_A(A2, (s + 2) << 5);
    compute(A0, B0);
    unsigned short* tA = A0; A0 = A1; A1 = A2; A2 = tA;
    unsigned short* tB = B0; B0 = B1; B1 = tB;
  }
  asm volatile("s_waitcnt vmcnt(0)" ::: "memory");
  __builtin_amdgcn_s_barrier();
  __builtin_amdgcn_sched_barrier(0);
  compute(A0, B0);

  // ---- epilogue setup: aliased LDS is dead now; barrier before reuse ----
  __syncthreads();
  col_s[t] = 0.f;
  if (t < 128) {
    const int m = m0 + t;
    dws[t] = (m < M) ? degw[m] : 0.f;
    gbs[t] = (m < M) ? batch[m] : -1;
  }
  __syncthreads();

  float uu[4], vv[4];
#pragma unroll
  for (int j = 0; j < 4; ++j) {
    const int n = n0 + wn + j * 16 + l16;
    uu[j] = u[n]; vv[j] = v[n];
  }

  // ---- single-pass epilogue: activation + hp write + BN sums + register pooling ----
  const bool wout = (outH != nullptr);
  const int lastr = min(127, M - 1 - m0);
  const int gmin = gbs[0];
  const int gmax = gbs[lastr];

  float ts[4]  = {0.f, 0.f, 0.f, 0.f};
  float tss[4] = {0.f, 0.f, 0.f, 0.f};
  float px0[4], pn0[4], ps0[4], px1[4], pn1[4], ps1[4];
#pragma unroll
  for (int j = 0; j < 4; ++j) {
    px0[j] = FNEG; pn0[j] = FPOS; ps0[j] = 0.f;
    px1[j] = FNEG; pn1[j] = FPOS; ps1[j] = 0.f;
  }

#pragma unroll
  for (int i = 0; i < 4; ++i) {
    const int lrow2 = wm + i * 16 + lq * 4;
#pragma unroll
    for (int r = 0; r < 4; ++r) {
      const int row = lrow2 + r;
      const bool live = (m0 + row < M);
      const int gv = gbs[row];
      const float dwr = dws[row];
      const bool in0 = live && (gv == gmin);
      const bool in1 = live && (gmax != gmin) && (gv == gmax);
#pragma unroll
      for (int j = 0; j < 4; ++j) {
        const int n = n0 + wn + j * 16 + l16;
        float val = acc[i][j][r] + vv[j] + dwr * uu[j];
        val = val > 0.f ? val : LEAKY * val;
        acc[i][j][r] = val;
        if (live) {
          if (wout) outH[(size_t)(m0 + row) * N + n] = f2b(val);
          ts[j]  += val;
          tss[j] += val * val;
        }
        if (in0) { px0[j] = fmaxf(px0[j], val); pn0[j] = fminf(pn0[j], val); ps0[j] += val; }
        if (in1) { px1[j] = fmaxf(px1[j], val); pn1[j] = fminf(pn1[j], val); ps1[j] += val; }
      }
    }
  }

  const int half = w & 1;
#pragma unroll
  for (int j = 0; j < 4; ++j) {
    float a = ts[j], b = tss[j];
    a += __shfl_xor(a, 16); a += __shfl_xor(a, 32);
    b += __shfl_xor(b, 16); b += __shfl_xor(b, 32);
    float x0 = px0[j], n0v = pn0[j], s0v = ps0[j];
    x0 = fmaxf(x0, __shfl_xor(x0, 16)); x0 = fmaxf(x0, __shfl_xor(x0, 32));
    n0v = fminf(n0v, __shfl_xor(n0v, 16)); n0v = fminf(n0v, __shfl_xor(n0v, 32));
    s0v += __shfl_xor(s0v, 16); s0v += __shfl_xor(s0v, 32);
    float x1 = px1[j], n1v = pn1[j], s1v = ps1[j];
    x1 = fmaxf(x1, __shfl_xor(x1, 16)); x1 = fmaxf(x1, __shfl_xor(x1, 32));
    n1v = fminf(n1v, __shfl_xor(n1v, 16)); n1v = fminf(n1v, __shfl_xor(n1v, 32));
    s1v += __shfl_xor(s1v, 16); s1v += __shfl_xor(s1v, 32);
    if (lq == 0) {
      const int ci = wn + j * 16 + l16;
      atomicAdd(&col_s[ci], a);
      atomicAdd(&col_s[128 + ci], b);
      const size_t tb = (size_t)(m_tile * NT + nt2) * 2;
      const size_t sb0 = ((tb + 0) * 2 + half) * 128 + ci;
      const size_t sb1 = ((tb + 1) * 2 + half) * 128 + ci;
      ppmax[sb0] = x0;  ppmin[sb0] = n0v; ppsum[sb0] = s0v;
      ppmax[sb1] = x1;  ppmin[sb1] = n1v; ppsum[sb1] = s1v;
    }
  }

  // cold fallback: block spans >2 graphs (never for ~195-row graphs) -> global atomics
  if (gmax > gmin + 1) {
    for (int g = gmin + 1; g < gmax; ++g) {
#pragma unroll
      for (int j = 0; j < 4; ++j) {
        float mx = FNEG, mn = FPOS, sm = 0.f;
#pragma unroll
        for (int i = 0; i < 4; ++i) {
          const int lrow2 = wm + i * 16 + lq * 4;
#pragma unroll
          for (int r = 0; r < 4; ++r) {
            const int row = lrow2 + r;
            if (m0 + row < M && gbs[row] == g) {
              const float val = acc[i][j][r];
              mx = fmaxf(mx, val); mn = fminf(mn, val); sm += val;
            }
          }
        }
        mx = fmaxf(mx, __shfl_xor(mx, 16)); mx = fmaxf(mx, __shfl_xor(mx, 32));
        mn = fminf(mn, __shfl_xor(mn, 16)); mn = fminf(mn, __shfl_xor(mn, 32));
        sm += __shfl_xor(sm, 16); sm += __shfl_xor(sm, 32);
        if (lq == 0 && mx > -3.3e38f) {
          const size_t pi = (size_t)g * N + (n0 + wn + j * 16 + l16);
          atomicMax(&pmaxk[pi], fkey(mx));
          atomicMin(&pmink[pi], fkey(mn));
          atomicAdd(&psumg[pi], sm);
        }
      }
    }
  }

  __syncthreads();
  if (t < 128) {
    atomicAdd(&sums[n0 + t], col_s[t]);
    atomicAdd(&sums[N + n0 + t], col_s[128 + t]);
  }
}

// ---------------- combined pool finalize: merge privatized partials + fallback ----------

__global__ void pool_finalize_all_kernel(const unsigned* __restrict__ pmaxk,
                                         const unsigned* __restrict__ pmink,
                                         const float* __restrict__ psumg,
                                         const float* __restrict__ ppmax,
                                         const float* __restrict__ ppmin,
                                         const float* __restrict__ ppsum,
                                         const float* __restrict__ sums_all,
                                         const float* __restrict__ gamma1, const float* __restrict__ beta1,
                                         const float* __restrict__ gamma2, const float* __restrict__ beta2,
                                         const float* __restrict__ gamma3, const float* __restrict__ beta3,
                                         const int* __restrict__ gptr,
                                         const int* __restrict__ batch,
                                         float* __restrict__ z) {
  int i = blockIdx.x * blockDim.x + threadIdx.x;
  if (i >= POOL_TOT) return;
  int C, zoff, li, NTL;
  size_t ppo;
  const float *sums, *gamma, *beta;
  if (i < N_GRAPH * 128) {
    C = 128; zoff = 0; li = i; NTL = 1; ppo = 0;
    sums = sums_all; gamma = gamma1; beta = beta1;
  } else if (i < N_GRAPH * (128 + 256)) {
    C = 256; zoff = 384; li = i - N_GRAPH * 128; NTL = 2; ppo = PP_L1;
    sums = sums_all + 2 * 128; gamma = gamma2; beta = beta2;
  } else {
    C = 384; zoff = 1152; li = i - N_GRAPH * (128 + 256); NTL = 3; ppo = PP_L1 + PP_L2;
    sums = sums_all + 2 * (128 + 256); gamma = gamma3; beta = beta3;
  }
  const int g = li / C, c = li % C;
  const int cnt = gptr[g + 1] - gptr[g];

  // merge fallback atomics (neutral unless a block spanned >2 graphs)
  float mx = FNEG, mn = FPOS, sm = psumg[i];
  {
    const unsigned pk = pmaxk[i];
    if (pk != 0u) mx = kdec(pk);
    const unsigned nk = pmink[i];
    if (nk != 0xFFFFFFFFu) mn = kdec(nk);
  }
  // merge privatized per-(m_tile, gslot, half) partials
  if (cnt > 0) {
    const int mt_lo = gptr[g] >> 7;
    const int mt_hi = (gptr[g + 1] - 1) >> 7;
    const int nt = c >> 7, cc = c & 127;
    for (int mt = mt_lo; mt <= mt_hi; ++mt) {
      const int g0 = batch[mt << 7];
      int grel = (g == g0) ? 0 : -1;
      if (grel < 0) {
        const int lastm = min((mt << 7) + 127, N_NODES - 1);
        if (g == batch[lastm]) grel = 1;
      }
      if (grel >= 0) {
        const size_t b0 = ppo + (((size_t)(mt * NTL + nt) * 2 + grel) * 2 + 0) * 128 + cc;
        const size_t b1 = b0 + 128;
        mx = fmaxf(mx, fmaxf(ppmax[b0], ppmax[b1]));
        mn = fminf(mn, fminf(ppmin[b0], ppmin[b1]));
        sm += ppsum[b0] + ppsum[b1];
      }
    }
  }

  const float inv_n = 1.f / (float)N_NODES;
  const float mu  = sums[c] * inv_n;
  const float var = sums[C + c] * inv_n - mu * mu;
  const float sc  = rsqrtf(var + BN_EPS) * gamma[c];
  const float sh  = beta[c] - mu * sc;
  const float zmax = (sc >= 0.f ? mx : mn) * sc + sh;
  const float zsum = sm * sc + (float)cnt * sh;
  float* zg = z + (size_t)g * Z_DIM + zoff;
  zg[c]         = (cnt > 0) ? zmax : 0.f;
  zg[C + c]     = zsum / (float)(cnt > 0 ? cnt : 1);
  zg[2 * C + c] = zsum;
}

// ---------------- FC head ----------------

__global__ __launch_bounds__(1024) void fc_kernel(const float* __restrict__ z,
                                                  const float* __restrict__ w1, const float* __restrict__ b1,
                                                  const float* __restrict__ w2, const float* __restrict__ b2,
                                                  const float* __restrict__ w3, const float* __restrict__ b3,
                                                  float* __restrict__ out) {
  __shared__ float zs[Z_DIM];
  __shared__ float part[8][128];
  __shared__ float h1s[128];
  __shared__ float red[128][2];
  __shared__ float y2[2];
  const int g  = blockIdx.x;
  const int t  = threadIdx.x;
  const int c  = t & 127;
  const int ks = t >> 7;
  for (int i = t; i < Z_DIM; i += 1024) zs[i] = z[(size_t)g * Z_DIM + i];
  __syncthreads();

  constexpr int KCH = Z_DIM / 8;
  const int k0 = ks * KCH;
  float acc = 0.f;
#pragma unroll 4
  for (int k = k0; k < k0 + KCH; ++k) acc += zs[k] * w1[(size_t)k * 128 + c];
  part[ks][c] = acc;
  __syncthreads();

  if (t < 128) {
    float s = b1[t];
#pragma unroll
    for (int i = 0; i < 8; ++i) s += part[i][t];
    h1s[t] = fmaxf(s, 0.f);
  }
  __syncthreads();
  if (t < 128) {
    red[t][0] = h1s[t] * w2[t * 2 + 0];
    red[t][1] = h1s[t] * w2[t * 2 + 1];
  }
  __syncthreads();
  if (t < 2) {
    float s = b2[t];
    for (int k = 0; k < 128; ++k) s += red[k][t];
    y2[t] = fmaxf(s, 0.f);
  }
  __syncthreads();
  if (t == 0) {
    const float z0 = y2[0] * w3[0] + y2[1] * w3[2] + b3[0];
    const float z1 = y2[0] * w3[1] + y2[1] * w3[3] + b3[1];
    const float m  = fmaxf(z0, z1);
    const float lse = m + logf(expf(z0 - m) + expf(z1 - m));
    out[g * 2 + 0] = z0 - lse;
    out[g * 2 + 1] = z1 - lse;
  }
}

// ---------------- launch ----------------

extern "C" void kernel_launch(void* const* d_in, const int* in_sizes, int n_in,
                              void* d_out, int out_size, void* d_ws, size_t ws_size,
                              hipStream_t stream) {
  (void)in_sizes; (void)n_in; (void)out_size; (void)ws_size;
  const float* x        = (const float*)d_in[0];
  const int*   eidx     = (const int*)d_in[1];
  const int*   batch    = (const int*)d_in[2];
  const float* eattr    = (const float*)d_in[3];
  const float* w_rel1   = (const float*)d_in[4];
  const float* b_rel1   = (const float*)d_in[5];
  const float* w_root1  = (const float*)d_in[6];
  const float* w_rel2   = (const float*)d_in[7];
  const float* b_rel2   = (const float*)d_in[8];
  const float* w_root2  = (const float*)d_in[9];
  const float* w_rel3   = (const float*)d_in[10];
  const float* b_rel3   = (const float*)d_in[11];
  const float* w_root3  = (const float*)d_in[12];
  const float* gamma1   = (const float*)d_in[13];
  const float* beta1    = (const float*)d_in[14];
  const float* gamma2   = (const float*)d_in[15];
  const float* beta2    = (const float*)d_in[16];
  const float* gamma3   = (const float*)d_in[17];
  const float* beta3    = (const float*)d_in[18];
  const float* w_lin1   = (const float*)d_in[19];
  const float* b_lin1   = (const float*)d_in[20];
  const float* w_lin2   = (const float*)d_in[21];
  const float* b_lin2   = (const float*)d_in[22];
  const float* w_lin3   = (const float*)d_in[23];
  const float* b_lin3   = (const float*)d_in[24];

  const int* src = eidx;
  const int* dst = eidx + N_EDGES;
  float* outp = (float*)d_out;

  char* ws = (char*)d_ws;
  size_t off = 0;
  auto alloc = [&](size_t bytes) -> void* {
    void* p = ws + off;
    off += (bytes + 255) & ~(size_t)255;
    return p;
  };
  int*   rowptr = (int*)alloc((N_NODES + 1) * sizeof(int));
  int*   cntR   = (int*)alloc((size_t)NREP * N_NODES * sizeof(int));
  int*   gptr   = (int*)alloc((N_GRAPH + 1) * sizeof(int));
  int*   gcnt   = (int*)alloc(N_GRAPH * sizeof(int));
  int*   part   = (int*)alloc(256 * sizeof(int));
  ull*   epack  = (ull*)alloc((size_t)N_EDGES * sizeof(ull));
  float* degw   = (float*)alloc(N_NODES * sizeof(float));
  float* sums_all = (float*)alloc(2 * (128 + 256 + 384) * sizeof(float));
  float* zbuf   = (float*)alloc((size_t)N_GRAPH * Z_DIM * sizeof(float));
  unsigned* pmaxk = (unsigned*)alloc((size_t)POOL_TOT * 4);
  unsigned* pmink = (unsigned*)alloc((size_t)POOL_TOT * 4);
  float*    psumg = (float*)alloc((size_t)POOL_TOT * 4);
  float* ppmax = (float*)alloc((size_t)PP_TOT * 4);
  float* ppmin = (float*)alloc((size_t)PP_TOT * 4);
  float* ppsum = (float*)alloc((size_t)PP_TOT * 4);
  unsigned short* xb   = (unsigned short*)alloc((size_t)M_PAD * 128 * 2);
  unsigned short* hp1  = (unsigned short*)alloc((size_t)M_PAD * 128 * 2);
  unsigned short* hp2  = (unsigned short*)alloc((size_t)M_PAD * 256 * 2);
  unsigned short* aggb = (unsigned short*)alloc((size_t)M_PAD * 256 * 2);
  unsigned short* wt1 = (unsigned short*)alloc((size_t)128 * 256 * 2);
  unsigned short* wt2 = (unsigned short*)alloc((size_t)256 * 256 * 2);
  unsigned short* wt3 = (unsigned short*)alloc((size_t)384 * 512 * 2);
  float* u1 = (float*)alloc(128 * sizeof(float));
  float* v1 = (float*)alloc(128 * sizeof(float));
  float* u2 = (float*)alloc(256 * sizeof(float));
  float* v2 = (float*)alloc(256 * sizeof(float));
  float* u3 = (float*)alloc(384 * sizeof(float));
  float* v3 = (float*)alloc(384 * sizeof(float));

  float* sums1 = sums_all;
  float* sums2 = sums_all + 2 * 128;
  float* sums3 = sums_all + 2 * (128 + 256);
  const int PO1 = 0, PO2 = N_GRAPH * 128, PO3 = N_GRAPH * (128 + 256);

  const int EB = (N_EDGES + 255) / 256;
  const int NB = (N_NODES + 255) / 256;
  const int SB = (N_NODES + 1023) / 1024;

  init_all_kernel<<<(NREP * N_NODES + 255) / 256, 256, 0, stream>>>(
      cntR, gcnt, sums_all, pmaxk, pmink, psumg);

  // ---- CSR by dst ----
  hist_rep_kernel<<<EB, 256, 0, stream>>>(dst, cntR, N_EDGES);
  scan1_fused_kernel<<<SB, 256, 0, stream>>>(cntR, rowptr, part, N_NODES);
  scan2_kernel<<<1, 256, 0, stream>>>(part, SB, rowptr + N_NODES);
  scan3_cursor_kernel<<<NB, 256, 0, stream>>>(rowptr, part, cntR, N_NODES);
  bucket_kernel<<<EB, 256, 0, stream>>>(src, dst, eattr, cntR, epack, N_EDGES);

  // ---- graph segment pointers ----
  hist_batch_kernel<<<NB, 256, 0, stream>>>(batch, gcnt, N_NODES);
  scan256_kernel<<<1, 256, 0, stream>>>(gcnt, gptr);

  // ---- prep ----
  cast_bf16_kernel<<<(N_NODES * 128 / 2 + 255) / 256, 256, 0, stream>>>(x, xb, N_NODES * 128 / 2);
  wt_build_kernel<<<128, 256, 0, stream>>>(w_rel1, w_root1, b_rel1, nullptr, nullptr, nullptr,
                                           wt1, u1, v1, 128, 128);

  const int aggBlocks = (N_NODES * 64 + 255) / 256;

  // ---- layer 1: 128 -> 128 ----
  agg_bf16_kernel<128><<<aggBlocks, 256, 0, stream>>>(xb, rowptr, epack, aggb, degw);
  gemm_mfma_kernel<<<392 * 1, 256, 0, stream>>>(aggb, xb, wt1, u1, v1, degw, batch,
                                                hp1, sums1, pmaxk + PO1, pmink + PO1,
                                                psumg + PO1, ppmax, ppmin, ppsum,
                                                N_NODES, 128, 128);
  wt_build_kernel<<<256, 256, 0, stream>>>(w_rel2, w_root2, b_rel2, sums1, gamma1, beta1,
                                           wt2, u2, v2, 128, 256);

  // ---- layer 2: 128 -> 256 ----
  agg_bf16_kernel<128><<<aggBlocks, 256, 0, stream>>>(hp1, rowptr, epack, aggb, nullptr);
  gemm_mfma_kernel<<<392 * 2, 256, 0, stream>>>(aggb, hp1, wt2, u2, v2, degw, batch,
                                                hp2, sums2, pmaxk + PO2, pmink + PO2,
                                                psumg + PO2, ppmax + PP_L1, ppmin + PP_L1,
                                                ppsum + PP_L1, N_NODES, 128, 256);
  wt_build_kernel<<<384, 256, 0, stream>>>(w_rel3, w_root3, b_rel3, sums2, gamma2, beta2,
                                           wt3, u3, v3, 256, 384);

  // ---- layer 3: 256 -> 384 (no hp3 write: pooling fused, output unused) ----
  agg_bf16_kernel<256><<<aggBlocks, 256, 0, stream>>>(hp2, rowptr, epack, aggb, nullptr);
  gemm_mfma_kernel<<<392 * 3, 256, 0, stream>>>(aggb, hp2, wt3, u3, v3, degw, batch,
                                                (unsigned short*)nullptr, sums3,
                                                pmaxk + PO3, pmink + PO3, psumg + PO3,
                                                ppmax + PP_L1 + PP_L2, ppmin + PP_L1 + PP_L2,
                                                ppsum + PP_L1 + PP_L2, N_NODES, 256, 384);

  // ---- combined pool finalize (all layers) + FC head ----
  pool_finalize_all_kernel<<<(POOL_TOT + 255) / 256, 256, 0, stream>>>(
      pmaxk, pmink, psumg, ppmax, ppmin, ppsum, sums_all,
      gamma1, beta1, gamma2, beta2, gamma3, beta3, gptr, batch, zbuf);
  fc_kernel<<<N_GRAPH, 1024, 0, stream>>>(zbuf, w_lin1, b_lin1, w_lin2, b_lin2, w_lin3, b_lin3,
                                          outp);
}

// Round 11
// 483.725 us; speedup vs baseline: 1.1438x; 1.0329x over previous
//
#include <hip/hip_runtime.h>
#include <cstdint>
#include <cstddef>

#define N_NODES 50000
#define M_PAD   50048   // 391 * 128
#define MB_TILES 391
#define N_EDGES 800000
#define N_GRAPH 256
#define Z_DIM   2304
#define NREP    16
#define POOL_TOT (N_GRAPH * (128 + 256 + 384))
// privatized pooling partials: per (m_tile, n_tile, gslot{0,1}, half{0,1}) x 128 cols
#define PP_L1 (MB_TILES * 1 * 2 * 2 * 128)   // 200192
#define PP_L2 (MB_TILES * 2 * 2 * 2 * 128)   // 400384
#define PP_L3 (MB_TILES * 3 * 2 * 2 * 128)   // 600576
#define PP_TOT (PP_L1 + PP_L2 + PP_L3)

static constexpr float LEAKY  = 0.01f;
static constexpr float BN_EPS = 1e-5f;
static constexpr float FNEG   = -3.4e38f;
static constexpr float FPOS   =  3.4e38f;

typedef short short8 __attribute__((ext_vector_type(8)));
typedef float floatx4 __attribute__((ext_vector_type(4)));
typedef const __attribute__((address_space(1))) unsigned int* gas_ptr;
typedef __attribute__((address_space(3))) unsigned int* las_ptr;
typedef unsigned long long ull;

__device__ __forceinline__ unsigned short f2b(float f) {
  union { float f; unsigned int u; } v; v.f = f;
  unsigned int u = v.u;
  unsigned int r = (u + 0x7FFFu + ((u >> 16) & 1u)) >> 16;
  return (unsigned short)r;
}
__device__ __forceinline__ float b2f(unsigned short h) {
  union { unsigned int u; float f; } v; v.u = ((unsigned int)h) << 16;
  return v.f;
}
__device__ __forceinline__ unsigned fkey(float x) {
  unsigned k = __float_as_uint(x);
  return k ^ ((k & 0x80000000u) ? 0xFFFFFFFFu : 0x80000000u);
}
__device__ __forceinline__ float kdec(unsigned k) {
  k ^= (k & 0x80000000u) ? 0x80000000u : 0xFFFFFFFFu;
  return __uint_as_float(k);
}

// ---------------- one-shot init ----------------

__global__ void init_all_kernel(int* __restrict__ cntR, int* __restrict__ gcnt,
                                float* __restrict__ sums_all,
                                unsigned* __restrict__ pmaxk, unsigned* __restrict__ pmink,
                                float* __restrict__ psumg) {
  const int i = blockIdx.x * blockDim.x + threadIdx.x;
  if (i < NREP * N_NODES) cntR[i] = 0;
  if (i < N_GRAPH) gcnt[i] = 0;
  if (i < 2 * (128 + 256 + 384)) sums_all[i] = 0.f;
  if (i < POOL_TOT) { pmaxk[i] = 0u; pmink[i] = 0xFFFFFFFFu; psumg[i] = 0.f; }
}

// ---------------- CSR build (replicated histogram/cursor) ----------------

__global__ void hist_rep_kernel(const int* __restrict__ idx, int* __restrict__ cntR, int n) {
  int i = blockIdx.x * blockDim.x + threadIdx.x;
  if (i < n) {
    const int rep = blockIdx.x & (NREP - 1);
    atomicAdd(&cntR[rep * N_NODES + idx[i]], 1);
  }
}

// scan phase 1 fused with replica combine.
__global__ __launch_bounds__(256) void scan1_fused_kernel(int* __restrict__ cntR,
                                                          int* __restrict__ out,
                                                          int* __restrict__ part, int n) {
  __shared__ int sm[256];
  const int t = threadIdx.x;
  const int base = blockIdx.x * 1024 + t * 4;
  int v[4] = {0, 0, 0, 0};
#pragma unroll
  for (int j = 0; j < 4; ++j) {
    const int d = base + j;
    if (d < n) {
      int s = 0;
#pragma unroll
      for (int r = 0; r < NREP; ++r) {
        const int c = cntR[r * N_NODES + d];
        cntR[r * N_NODES + d] = s;
        s += c;
      }
      v[j] = s;
    }
  }
  const int tsum = v[0] + v[1] + v[2] + v[3];
  sm[t] = tsum;
  __syncthreads();
  for (int off = 1; off < 256; off <<= 1) {
    int x = (t >= off) ? sm[t - off] : 0;
    __syncthreads();
    sm[t] += x;
    __syncthreads();
  }
  const int excl = sm[t] - tsum;
  if (base     < n) out[base]     = excl;
  if (base + 1 < n) out[base + 1] = excl + v[0];
  if (base + 2 < n) out[base + 2] = excl + v[0] + v[1];
  if (base + 3 < n) out[base + 3] = excl + v[0] + v[1] + v[2];
  if (t == 255) part[blockIdx.x] = sm[255];
}

__global__ __launch_bounds__(256) void scan2_kernel(int* __restrict__ part, int nb,
                                                    int* __restrict__ total_out) {
  __shared__ int sm[256];
  const int t = threadIdx.x;
  const int v = (t < nb) ? part[t] : 0;
  sm[t] = v;
  __syncthreads();
  for (int off = 1; off < 256; off <<= 1) {
    int x = (t >= off) ? sm[t - off] : 0;
    __syncthreads();
    sm[t] += x;
    __syncthreads();
  }
  if (t < nb) part[t] = sm[t] - v;
  if (t == 255) *total_out = sm[255];
}

__global__ void scan3_cursor_kernel(int* __restrict__ out, const int* __restrict__ part,
                                    int* __restrict__ cntR, int n) {
  int i = blockIdx.x * blockDim.x + threadIdx.x;
  if (i >= n) return;
  const int rp = out[i] + part[i >> 10];
  out[i] = rp;
#pragma unroll
  for (int r = 0; r < NREP; ++r) cntR[r * N_NODES + i] += rp;
}

__global__ void bucket_kernel(const int* __restrict__ src, const int* __restrict__ dst,
                              const float* __restrict__ ew, int* __restrict__ cntR,
                              ull* __restrict__ epack, int E) {
  int e = blockIdx.x * blockDim.x + threadIdx.x;
  if (e < E) {
    const int rep = blockIdx.x & (NREP - 1);
    const int d = dst[e];
    const int p = atomicAdd(&cntR[rep * N_NODES + d], 1);
    epack[p] = ((ull)__float_as_uint(ew[e]) << 32) | (unsigned)src[e];
  }
}

__global__ __launch_bounds__(256) void hist_batch_kernel(const int* __restrict__ idx,
                                                         int* __restrict__ cnt, int n) {
  __shared__ int lh[N_GRAPH];
  lh[threadIdx.x] = 0;
  __syncthreads();
  int i = blockIdx.x * blockDim.x + threadIdx.x;
  if (i < n) atomicAdd(&lh[idx[i]], 1);
  __syncthreads();
  const int v = lh[threadIdx.x];
  if (v) atomicAdd(&cnt[threadIdx.x], v);
}

__global__ __launch_bounds__(256) void scan256_kernel(const int* __restrict__ cnt,
                                                      int* __restrict__ gptr) {
  __shared__ int sm[256];
  const int t = threadIdx.x;
  const int v = cnt[t];
  sm[t] = v;
  __syncthreads();
  for (int off = 1; off < 256; off <<= 1) {
    int x = (t >= off) ? sm[t - off] : 0;
    __syncthreads();
    sm[t] += x;
    __syncthreads();
  }
  gptr[t] = sm[t] - v;
  if (t == 255) gptr[256] = sm[255];
}

// ---------------- prep: fused cast (blocks >= 128) + layer-1 wt_build (blocks < 128) ----

__global__ __launch_bounds__(256) void prep1_kernel(
    const float* __restrict__ x, unsigned short* __restrict__ xb, int npair,
    const float* __restrict__ wrel, const float* __restrict__ wroot,
    const float* __restrict__ brel,
    unsigned short* __restrict__ wt, float* __restrict__ u, float* __restrict__ v) {
  if (blockIdx.x >= 128) {
    const int i = (blockIdx.x - 128) * 256 + threadIdx.x;
    if (i < npair) {
      float2 vv = *(const float2*)(x + 2 * (size_t)i);
      ((unsigned int*)xb)[i] = (unsigned int)f2b(vv.x) | ((unsigned int)f2b(vv.y) << 16);
    }
    return;
  }
  // wt_build for layer 1 (K=128, N=128, no BN folding)
  __shared__ float redu[256];
  __shared__ float redv[256];
  const int n = blockIdx.x;
  const int K = 128, N = 128, K2 = 256;
  float us = 0.f, vs = 0.f;
  for (int k = threadIdx.x; k < K2; k += 256) {
    const int kk = (k < K) ? k : k - K;
    const float w = (k < K) ? wrel[(size_t)kk * N + n] : wroot[(size_t)kk * N + n];
    wt[(size_t)n * K2 + k] = f2b(w);
    (void)kk;
  }
  redu[threadIdx.x] = us; redv[threadIdx.x] = vs;
  __syncthreads();
  for (int o = 128; o > 0; o >>= 1) {
    if (threadIdx.x < o) {
      redu[threadIdx.x] += redu[threadIdx.x + o];
      redv[threadIdx.x] += redv[threadIdx.x + o];
    }
    __syncthreads();
  }
  if (threadIdx.x == 0) { u[n] = redu[0]; v[n] = brel[n] + redv[0]; }
}

__global__ __launch_bounds__(256) void wt_build_kernel(
    const float* __restrict__ wrel, const float* __restrict__ wroot,
    const float* __restrict__ brel, const float* __restrict__ sums_prev,
    const float* __restrict__ gamma_prev, const float* __restrict__ beta_prev,
    unsigned short* __restrict__ wt, float* __restrict__ u, float* __restrict__ v,
    int K, int N) {
  __shared__ float redu[256];
  __shared__ float redv[256];
  const int n = blockIdx.x;
  const int K2 = 2 * K;
  const float inv_n = 1.f / (float)N_NODES;
  float us = 0.f, vs = 0.f;
  for (int k = threadIdx.x; k < K2; k += 256) {
    const int kk = (k < K) ? k : k - K;
    const float w = (k < K) ? wrel[(size_t)kk * N + n] : wroot[(size_t)kk * N + n];
    float sc = 1.f, sh = 0.f;
    if (sums_prev) {
      const float mu  = sums_prev[kk] * inv_n;
      const float var = sums_prev[K + kk] * inv_n - mu * mu;
      sc = rsqrtf(var + BN_EPS) * gamma_prev[kk];
      sh = beta_prev[kk] - mu * sc;
    }
    wt[(size_t)n * K2 + k] = f2b(w * sc);
    if (k < K) us += sh * w; else vs += sh * w;
  }
  redu[threadIdx.x] = us; redv[threadIdx.x] = vs;
  __syncthreads();
  for (int o = 128; o > 0; o >>= 1) {
    if (threadIdx.x < o) {
      redu[threadIdx.x] += redu[threadIdx.x + o];
      redv[threadIdx.x] += redv[threadIdx.x + o];
    }
    __syncthreads();
  }
  if (threadIdx.x == 0) { u[n] = redu[0]; v[n] = brel[n] + redv[0]; }
}

// ---------------- aggregation: MLP-maximized gather (at its pattern roofline) --------

template <int D>
__global__ void agg_bf16_kernel(const unsigned short* __restrict__ h,
                                const int* __restrict__ rowptr,
                                const ull* __restrict__ epack,
                                unsigned short* __restrict__ agg,
                                float* __restrict__ degw_out) {
  int gid  = blockIdx.x * blockDim.x + threadIdx.x;
  int node = gid >> 6;
  int lane = threadIdx.x & 63;
  if (node >= N_NODES) return;
  const int beg = rowptr[node], end = rowptr[node + 1];
  constexpr int NP = D / 128;
  float acc0[NP], acc1[NP];
#pragma unroll
  for (int i = 0; i < NP; ++i) { acc0[i] = 0.f; acc1[i] = 0.f; }
  float wsum = 0.f;

  for (int c0 = beg; c0 < end; c0 += 64) {
    const int cn = min(64, end - c0);
    ull pk = 0;  // pad: src=0, w=0
    if (lane < cn) pk = epack[c0 + lane];
    const int   su = (int)(unsigned)pk;
    const float wf = __uint_as_float((unsigned)(pk >> 32));
    const int ng = (cn + 7) >> 3;  // groups of 8, padded
    for (int g = 0; g < ng; ++g) {
      int ss[8]; float wv[8];
#pragma unroll
      for (int j = 0; j < 8; ++j) {
        ss[j] = __shfl(su, g * 8 + j);
        wv[j] = __shfl(wf, g * 8 + j);
      }
      unsigned uu[8][NP];
#pragma unroll
      for (int j = 0; j < 8; ++j) {
        const unsigned int* row = (const unsigned int*)(h + (size_t)ss[j] * D);
#pragma unroll
        for (int i = 0; i < NP; ++i) uu[j][i] = row[lane + 64 * i];
      }
#pragma unroll
      for (int j = 0; j < 8; ++j) {
        wsum += wv[j];
#pragma unroll
        for (int i = 0; i < NP; ++i) {
          acc0[i] += b2f((unsigned short)(uu[j][i] & 0xFFFF)) * wv[j];
          acc1[i] += b2f((unsigned short)(uu[j][i] >> 16)) * wv[j];
        }
      }
    }
  }

  unsigned int* o = (unsigned int*)(agg + (size_t)node * D);
#pragma unroll
  for (int i = 0; i < NP; ++i)
    o[lane + 64 * i] = (unsigned int)f2b(acc0[i]) | ((unsigned int)f2b(acc1[i]) << 16);
  if (degw_out != nullptr && lane == 0) degw_out[node] = wsum;
}

// ---------------- MFMA GEMM with SINGLE-PASS fused pooling (round-10 validated) --------
// LDS 40KB (A triple / B double buffered), raw s_barrier + counted vmcnt(2),
// global_load_lds, XCD-affine tiles, BK=32. col_s/dws/gbs alias the A-buffers
// (dead after K-loop), initialized in the epilogue behind a barrier. Register
// pooling epilogue validated r7; B-debuffer validated r10 (gemm3 66.8 -> 60.0us).

__global__ __launch_bounds__(256) void gemm_mfma_kernel(
    const unsigned short* __restrict__ Aagg, const unsigned short* __restrict__ Ah,
    const unsigned short* __restrict__ Wt,
    const float* __restrict__ u, const float* __restrict__ v,
    const float* __restrict__ degw, const int* __restrict__ batch,
    unsigned short* __restrict__ outH, float* __restrict__ sums,
    unsigned* __restrict__ pmaxk, unsigned* __restrict__ pmink,
    float* __restrict__ psumg,
    float* __restrict__ ppmax, float* __restrict__ ppmin, float* __restrict__ ppsum,
    int M, int K, int N) {
  __shared__ char smem[40960];                                  // 24K A + 16K B
  unsigned short* AsBase = (unsigned short*)smem;               // 3 x 4096 shorts
  unsigned short* BsBase = (unsigned short*)(smem + 24576);     // 2 x 4096 shorts
  float* col_s = (float*)smem;            // epilogue-only, aliases As[0]
  float* dws   = (float*)(smem + 1024);   // epilogue-only
  int*   gbs   = (int*)(smem + 1536);     // epilogue-only

  const int NT = N >> 7;
  const int id = blockIdx.x;
  const int xcd = id & 7;
  const int q   = id >> 3;
  const int m_tile = (q / NT) * 8 + xcd;
  if (m_tile >= MB_TILES) return;
  const int m0 = m_tile * 128;
  const int nt2 = q % NT;
  const int n0 = nt2 * 128;

  const int t  = threadIdx.x;
  const int lane = t & 63;
  const int w    = t >> 6;
  const int wm   = (w & 1) * 64;
  const int wn   = (w >> 1) * 64;
  const int l16  = lane & 15;
  const int lq   = lane >> 4;
  const int K2   = 2 * K;

  const int lrow  = lane >> 2;
  const int lslot = lane & 3;

  floatx4 acc[4][4];
#pragma unroll
  for (int i = 0; i < 4; ++i)
#pragma unroll
    for (int j = 0; j < 4; ++j) acc[i][j] = (floatx4){0.f, 0.f, 0.f, 0.f};

  // stage one 128x32 A-tile (2 gload_lds/thread) for K-offset k0.
  auto stage_A = [&](unsigned short* Ab, int k0) {
    const unsigned short* Asrc;
    int kbase;
    if (k0 < K) { Asrc = Aagg; kbase = k0; } else { Asrc = Ah; kbase = k0 - K; }
#pragma unroll
    for (int qq = 0; qq < 2; ++qq) {
      const int row = w * 32 + qq * 16 + lrow;
      const int gc  = (lslot ^ ((row >> 1) & 3)) * 8;
      const unsigned short* gA = Asrc + (size_t)(m0 + row) * K + kbase + gc;
      __builtin_amdgcn_global_load_lds((gas_ptr)gA, (las_ptr)(Ab + (w * 32 + qq * 16) * 32),
                                       16, 0, 0);
    }
  };
  // stage one 128x32 B-tile (2 gload_lds/thread) for K-offset k0.
  auto stage_B = [&](unsigned short* Bb, int k0) {
#pragma unroll
    for (int qq = 0; qq < 2; ++qq) {
      const int row = w * 32 + qq * 16 + lrow;
      const int gc  = (lslot ^ ((row >> 1) & 3)) * 8;
      const unsigned short* gB = Wt + (size_t)(n0 + row) * K2 + k0 + gc;
      __builtin_amdgcn_global_load_lds((gas_ptr)gB, (las_ptr)(Bb + (w * 32 + qq * 16) * 32),
                                       16, 0, 0);
    }
  };

  // ds_read fragments from buffer and run the 4x4 MFMA block (setprio'd).
  auto compute = [&](const unsigned short* Ab, const unsigned short* Bb) {
    short8 af[4], bfr[4];
#pragma unroll
    for (int i = 0; i < 4; ++i) {
      const int r = wm + i * 16 + l16;
      af[i] = *(const short8*)(Ab + r * 32 + (lq ^ ((r >> 1) & 3)) * 8);
    }
#pragma unroll
    for (int j = 0; j < 4; ++j) {
      const int r = wn + j * 16 + l16;
      bfr[j] = *(const short8*)(Bb + r * 32 + (lq ^ ((r >> 1) & 3)) * 8);
    }
    __builtin_amdgcn_s_setprio(1);
#pragma unroll
    for (int i = 0; i < 4; ++i)
#pragma unroll
      for (int j = 0; j < 4; ++j)
        acc[i][j] = __builtin_amdgcn_mfma_f32_16x16x32_bf16(af[i], bfr[j], acc[i][j], 0, 0, 0);
    __builtin_amdgcn_s_setprio(0);
  };

  const int NSTEP = K2 >> 5;  // 8 or 16

  unsigned short *A0 = AsBase, *A1 = AsBase + 4096, *A2 = AsBase + 8192;
  unsigned short *B0 = BsBase, *B1 = BsBase + 4096;

  // prologue mimics steady-state issue order: A(0), B(0), A(1) -> 6 loads out
  stage_A(A0, 0);
  stage_B(B0, 0);
  stage_A(A1, 1 << 5);

  for (int s = 0; s < NSTEP - 1; ++s) {
    // wait until only the 2 newest (A(s+1)) remain -> A(s), B(s) landed
    asm volatile("s_waitcnt vmcnt(2)" ::: "memory");
    __builtin_amdgcn_s_barrier();
    __builtin_amdgcn_sched_barrier(0);
    stage_B(B1, (s + 1) << 5);                 // s+1 < NSTEP inside loop
    if (s + 2 < NSTEP) stage_A(A2, (s + 2) << 5);
    compute(A0, B0);
    unsigned short* tA = A0; A0 = A1; A1 = A2; A2 = tA;
    unsigned short* tB = B0; B0 = B1; B1 = tB;
  }
  asm volatile("s_waitcnt vmcnt(0)" ::: "memory");
  __builtin_amdgcn_s_barrier();
  __builtin_amdgcn_sched_barrier(0);
  compute(A0, B0);

  // ---- epilogue setup: aliased LDS is dead now; barrier before reuse ----
  __syncthreads();
  col_s[t] = 0.f;
  if (t < 128) {
    const int m = m0 + t;
    dws[t] = (m < M) ? degw[m] : 0.f;
    gbs[t] = (m < M) ? batch[m] : -1;
  }
  __syncthreads();

  float uu[4], vv[4];
#pragma unroll
  for (int j = 0; j < 4; ++j) {
    const int n = n0 + wn + j * 16 + l16;
    uu[j] = u[n]; vv[j] = v[n];
  }

  // ---- single-pass epilogue: activation + hp write + BN sums + register pooling ----
  const bool wout = (outH != nullptr);
  const int lastr = min(127, M - 1 - m0);
  const int gmin = gbs[0];
  const int gmax = gbs[lastr];

  float ts[4]  = {0.f, 0.f, 0.f, 0.f};
  float tss[4] = {0.f, 0.f, 0.f, 0.f};
  float px0[4], pn0[4], ps0[4], px1[4], pn1[4], ps1[4];
#pragma unroll
  for (int j = 0; j < 4; ++j) {
    px0[j] = FNEG; pn0[j] = FPOS; ps0[j] = 0.f;
    px1[j] = FNEG; pn1[j] = FPOS; ps1[j] = 0.f;
  }

#pragma unroll
  for (int i = 0; i < 4; ++i) {
    const int lrow2 = wm + i * 16 + lq * 4;
#pragma unroll
    for (int r = 0; r < 4; ++r) {
      const int row = lrow2 + r;
      const bool live = (m0 + row < M);
      const int gv = gbs[row];
      const float dwr = dws[row];
      const bool in0 = live && (gv == gmin);
      const bool in1 = live && (gmax != gmin) && (gv == gmax);
#pragma unroll
      for (int j = 0; j < 4; ++j) {
        const int n = n0 + wn + j * 16 + l16;
        float val = acc[i][j][r] + vv[j] + dwr * uu[j];
        val = val > 0.f ? val : LEAKY * val;
        acc[i][j][r] = val;
        if (live) {
          if (wout) outH[(size_t)(m0 + row) * N + n] = f2b(val);
          ts[j]  += val;
          tss[j] += val * val;
        }
        if (in0) { px0[j] = fmaxf(px0[j], val); pn0[j] = fminf(pn0[j], val); ps0[j] += val; }
        if (in1) { px1[j] = fmaxf(px1[j], val); pn1[j] = fminf(pn1[j], val); ps1[j] += val; }
      }
    }
  }

  const int half = w & 1;
#pragma unroll
  for (int j = 0; j < 4; ++j) {
    float a = ts[j], b = tss[j];
    a += __shfl_xor(a, 16); a += __shfl_xor(a, 32);
    b += __shfl_xor(b, 16); b += __shfl_xor(b, 32);
    float x0 = px0[j], n0v = pn0[j], s0v = ps0[j];
    x0 = fmaxf(x0, __shfl_xor(x0, 16)); x0 = fmaxf(x0, __shfl_xor(x0, 32));
    n0v = fminf(n0v, __shfl_xor(n0v, 16)); n0v = fminf(n0v, __shfl_xor(n0v, 32));
    s0v += __shfl_xor(s0v, 16); s0v += __shfl_xor(s0v, 32);
    float x1 = px1[j], n1v = pn1[j], s1v = ps1[j];
    x1 = fmaxf(x1, __shfl_xor(x1, 16)); x1 = fmaxf(x1, __shfl_xor(x1, 32));
    n1v = fminf(n1v, __shfl_xor(n1v, 16)); n1v = fminf(n1v, __shfl_xor(n1v, 32));
    s1v += __shfl_xor(s1v, 16); s1v += __shfl_xor(s1v, 32);
    if (lq == 0) {
      const int ci = wn + j * 16 + l16;
      atomicAdd(&col_s[ci], a);
      atomicAdd(&col_s[128 + ci], b);
      const size_t tb = (size_t)(m_tile * NT + nt2) * 2;
      const size_t sb0 = ((tb + 0) * 2 + half) * 128 + ci;
      const size_t sb1 = ((tb + 1) * 2 + half) * 128 + ci;
      ppmax[sb0] = x0;  ppmin[sb0] = n0v; ppsum[sb0] = s0v;
      ppmax[sb1] = x1;  ppmin[sb1] = n1v; ppsum[sb1] = s1v;
    }
  }

  // cold fallback: block spans >2 graphs (never for ~195-row graphs) -> global atomics
  if (gmax > gmin + 1) {
    for (int g = gmin + 1; g < gmax; ++g) {
#pragma unroll
      for (int j = 0; j < 4; ++j) {
        float mx = FNEG, mn = FPOS, sm = 0.f;
#pragma unroll
        for (int i = 0; i < 4; ++i) {
          const int lrow2 = wm + i * 16 + lq * 4;
#pragma unroll
          for (int r = 0; r < 4; ++r) {
            const int row = lrow2 + r;
            if (m0 + row < M && gbs[row] == g) {
              const float val = acc[i][j][r];
              mx = fmaxf(mx, val); mn = fminf(mn, val); sm += val;
            }
          }
        }
        mx = fmaxf(mx, __shfl_xor(mx, 16)); mx = fmaxf(mx, __shfl_xor(mx, 32));
        mn = fminf(mn, __shfl_xor(mn, 16)); mn = fminf(mn, __shfl_xor(mn, 32));
        sm += __shfl_xor(sm, 16); sm += __shfl_xor(sm, 32);
        if (lq == 0 && mx > -3.3e38f) {
          const size_t pi = (size_t)g * N + (n0 + wn + j * 16 + l16);
          atomicMax(&pmaxk[pi], fkey(mx));
          atomicMin(&pmink[pi], fkey(mn));
          atomicAdd(&psumg[pi], sm);
        }
      }
    }
  }

  __syncthreads();
  if (t < 128) {
    atomicAdd(&sums[n0 + t], col_s[t]);
    atomicAdd(&sums[N + n0 + t], col_s[128 + t]);
  }
}

// ---------------- fused pool finalize + FC head: one block per graph ----------------
// Finalize writes the 2304 z-entries of this graph directly into LDS (no global z
// roundtrip), then the FC head runs on them. Saves one dispatch + 2.4MB traffic.

__global__ __launch_bounds__(1024) void finalize_fc_kernel(
    const unsigned* __restrict__ pmaxk, const unsigned* __restrict__ pmink,
    const float* __restrict__ psumg,
    const float* __restrict__ ppmax, const float* __restrict__ ppmin,
    const float* __restrict__ ppsum,
    const float* __restrict__ sums_all,
    const float* __restrict__ gamma1, const float* __restrict__ beta1,
    const float* __restrict__ gamma2, const float* __restrict__ beta2,
    const float* __restrict__ gamma3, const float* __restrict__ beta3,
    const int* __restrict__ gptr, const int* __restrict__ batch,
    const float* __restrict__ w1, const float* __restrict__ b1,
    const float* __restrict__ w2, const float* __restrict__ b2,
    const float* __restrict__ w3, const float* __restrict__ b3,
    float* __restrict__ out) {
  __shared__ float zs[Z_DIM];
  __shared__ float part[8][128];
  __shared__ float h1s[128];
  __shared__ float red[128][2];
  __shared__ float y2[2];
  const int g = blockIdx.x;
  const int t = threadIdx.x;
  const int cnt = gptr[g + 1] - gptr[g];

  // ---- phase A: finalize 768 (layer,c) entries -> 2304 zs values ----
  if (t < 768) {
    int C, zoff, c, PO, NTL;
    size_t ppo;
    const float *sums, *gamma, *beta;
    if (t < 128) {
      C = 128; zoff = 0; c = t; PO = 0; NTL = 1; ppo = 0;
      sums = sums_all; gamma = gamma1; beta = beta1;
    } else if (t < 384) {
      C = 256; zoff = 384; c = t - 128; PO = N_GRAPH * 128; NTL = 2; ppo = PP_L1;
      sums = sums_all + 2 * 128; gamma = gamma2; beta = beta2;
    } else {
      C = 384; zoff = 1152; c = t - 384; PO = N_GRAPH * (128 + 256); NTL = 3;
      ppo = PP_L1 + PP_L2;
      sums = sums_all + 2 * (128 + 256); gamma = gamma3; beta = beta3;
    }
    const int i = PO + g * C + c;

    float mx = FNEG, mn = FPOS, sm = psumg[i];
    {
      const unsigned pk = pmaxk[i];
      if (pk != 0u) mx = kdec(pk);
      const unsigned nk = pmink[i];
      if (nk != 0xFFFFFFFFu) mn = kdec(nk);
    }
    if (cnt > 0) {
      const int mt_lo = gptr[g] >> 7;
      const int mt_hi = (gptr[g + 1] - 1) >> 7;
      const int nt = c >> 7, cc = c & 127;
      for (int mt = mt_lo; mt <= mt_hi; ++mt) {
        const int g0 = batch[mt << 7];
        int grel = (g == g0) ? 0 : -1;
        if (grel < 0) {
          const int lastm = min((mt << 7) + 127, N_NODES - 1);
          if (g == batch[lastm]) grel = 1;
        }
        if (grel >= 0) {
          const size_t b0 = ppo + (((size_t)(mt * NTL + nt) * 2 + grel) * 2 + 0) * 128 + cc;
          const size_t b1v = b0 + 128;
          mx = fmaxf(mx, fmaxf(ppmax[b0], ppmax[b1v]));
          mn = fminf(mn, fminf(ppmin[b0], ppmin[b1v]));
          sm += ppsum[b0] + ppsum[b1v];
        }
      }
    }

    const float inv_n = 1.f / (float)N_NODES;
    const float mu  = sums[c] * inv_n;
    const float var = sums[C + c] * inv_n - mu * mu;
    const float sc  = rsqrtf(var + BN_EPS) * gamma[c];
    const float sh  = beta[c] - mu * sc;
    const float zmax = (sc >= 0.f ? mx : mn) * sc + sh;
    const float zsum = sm * sc + (float)cnt * sh;
    zs[zoff + c]         = (cnt > 0) ? zmax : 0.f;
    zs[zoff + C + c]     = zsum / (float)(cnt > 0 ? cnt : 1);
    zs[zoff + 2 * C + c] = zsum;
  }
  __syncthreads();

  // ---- phase B: FC head (validated structure) ----
  const int c  = t & 127;
  const int ks = t >> 7;
  constexpr int KCH = Z_DIM / 8;
  const int k0 = ks * KCH;
  float acc = 0.f;
#pragma unroll 4
  for (int k = k0; k < k0 + KCH; ++k) acc += zs[k] * w1[(size_t)k * 128 + c];
  part[ks][c] = acc;
  __syncthreads();

  if (t < 128) {
    float s = b1[t];
#pragma unroll
    for (int i = 0; i < 8; ++i) s += part[i][t];
    h1s[t] = fmaxf(s, 0.f);
  }
  __syncthreads();
  if (t < 128) {
    red[t][0] = h1s[t] * w2[t * 2 + 0];
    red[t][1] = h1s[t] * w2[t * 2 + 1];
  }
  __syncthreads();
  if (t < 2) {
    float s = b2[t];
    for (int k = 0; k < 128; ++k) s += red[k][t];
    y2[t] = fmaxf(s, 0.f);
  }
  __syncthreads();
  if (t == 0) {
    const float z0 = y2[0] * w3[0] + y2[1] * w3[2] + b3[0];
    const float z1 = y2[0] * w3[1] + y2[1] * w3[3] + b3[1];
    const float m  = fmaxf(z0, z1);
    const float lse = m + logf(expf(z0 - m) + expf(z1 - m));
    out[g * 2 + 0] = z0 - lse;
    out[g * 2 + 1] = z1 - lse;
  }
}

// ---------------- launch ----------------

extern "C" void kernel_launch(void* const* d_in, const int* in_sizes, int n_in,
                              void* d_out, int out_size, void* d_ws, size_t ws_size,
                              hipStream_t stream) {
  (void)in_sizes; (void)n_in; (void)out_size; (void)ws_size;
  const float* x        = (const float*)d_in[0];
  const int*   eidx     = (const int*)d_in[1];
  const int*   batch    = (const int*)d_in[2];
  const float* eattr    = (const float*)d_in[3];
  const float* w_rel1   = (const float*)d_in[4];
  const float* b_rel1   = (const float*)d_in[5];
  const float* w_root1  = (const float*)d_in[6];
  const float* w_rel2   = (const float*)d_in[7];
  const float* b_rel2   = (const float*)d_in[8];
  const float* w_root2  = (const float*)d_in[9];
  const float* w_rel3   = (const float*)d_in[10];
  const float* b_rel3   = (const float*)d_in[11];
  const float* w_root3  = (const float*)d_in[12];
  const float* gamma1   = (const float*)d_in[13];
  const float* beta1    = (const float*)d_in[14];
  const float* gamma2   = (const float*)d_in[15];
  const float* beta2    = (const float*)d_in[16];
  const float* gamma3   = (const float*)d_in[17];
  const float* beta3    = (const float*)d_in[18];
  const float* w_lin1   = (const float*)d_in[19];
  const float* b_lin1   = (const float*)d_in[20];
  const float* w_lin2   = (const float*)d_in[21];
  const float* b_lin2   = (const float*)d_in[22];
  const float* w_lin3   = (const float*)d_in[23];
  const float* b_lin3   = (const float*)d_in[24];

  const int* src = eidx;
  const int* dst = eidx + N_EDGES;
  float* outp = (float*)d_out;

  char* ws = (char*)d_ws;
  size_t off = 0;
  auto alloc = [&](size_t bytes) -> void* {
    void* p = ws + off;
    off += (bytes + 255) & ~(size_t)255;
    return p;
  };
  int*   rowptr = (int*)alloc((N_NODES + 1) * sizeof(int));
  int*   cntR   = (int*)alloc((size_t)NREP * N_NODES * sizeof(int));
  int*   gptr   = (int*)alloc((N_GRAPH + 1) * sizeof(int));
  int*   gcnt   = (int*)alloc(N_GRAPH * sizeof(int));
  int*   part   = (int*)alloc(256 * sizeof(int));
  ull*   epack  = (ull*)alloc((size_t)N_EDGES * sizeof(ull));
  float* degw   = (float*)alloc(N_NODES * sizeof(float));
  float* sums_all = (float*)alloc(2 * (128 + 256 + 384) * sizeof(float));
  unsigned* pmaxk = (unsigned*)alloc((size_t)POOL_TOT * 4);
  unsigned* pmink = (unsigned*)alloc((size_t)POOL_TOT * 4);
  float*    psumg = (float*)alloc((size_t)POOL_TOT * 4);
  float* ppmax = (float*)alloc((size_t)PP_TOT * 4);
  float* ppmin = (float*)alloc((size_t)PP_TOT * 4);
  float* ppsum = (float*)alloc((size_t)PP_TOT * 4);
  unsigned short* xb   = (unsigned short*)alloc((size_t)M_PAD * 128 * 2);
  unsigned short* hp1  = (unsigned short*)alloc((size_t)M_PAD * 128 * 2);
  unsigned short* hp2  = (unsigned short*)alloc((size_t)M_PAD * 256 * 2);
  unsigned short* aggb = (unsigned short*)alloc((size_t)M_PAD * 256 * 2);
  unsigned short* wt1 = (unsigned short*)alloc((size_t)128 * 256 * 2);
  unsigned short* wt2 = (unsigned short*)alloc((size_t)256 * 256 * 2);
  unsigned short* wt3 = (unsigned short*)alloc((size_t)384 * 512 * 2);
  float* u1 = (float*)alloc(128 * sizeof(float));
  float* v1 = (float*)alloc(128 * sizeof(float));
  float* u2 = (float*)alloc(256 * sizeof(float));
  float* v2 = (float*)alloc(256 * sizeof(float));
  float* u3 = (float*)alloc(384 * sizeof(float));
  float* v3 = (float*)alloc(384 * sizeof(float));

  float* sums1 = sums_all;
  float* sums2 = sums_all + 2 * 128;
  float* sums3 = sums_all + 2 * (128 + 256);
  const int PO1 = 0, PO2 = N_GRAPH * 128, PO3 = N_GRAPH * (128 + 256);

  const int EB = (N_EDGES + 255) / 256;
  const int NB = (N_NODES + 255) / 256;
  const int SB = (N_NODES + 1023) / 1024;

  init_all_kernel<<<(NREP * N_NODES + 255) / 256, 256, 0, stream>>>(
      cntR, gcnt, sums_all, pmaxk, pmink, psumg);

  // ---- CSR by dst ----
  hist_rep_kernel<<<EB, 256, 0, stream>>>(dst, cntR, N_EDGES);
  scan1_fused_kernel<<<SB, 256, 0, stream>>>(cntR, rowptr, part, N_NODES);
  scan2_kernel<<<1, 256, 0, stream>>>(part, SB, rowptr + N_NODES);
  scan3_cursor_kernel<<<NB, 256, 0, stream>>>(rowptr, part, cntR, N_NODES);
  bucket_kernel<<<EB, 256, 0, stream>>>(src, dst, eattr, cntR, epack, N_EDGES);

  // ---- graph segment pointers ----
  hist_batch_kernel<<<NB, 256, 0, stream>>>(batch, gcnt, N_NODES);
  scan256_kernel<<<1, 256, 0, stream>>>(gcnt, gptr);

  // ---- prep: fused cast + layer-1 wt_build ----
  const int npair = N_NODES * 128 / 2;
  prep1_kernel<<<128 + (npair + 255) / 256, 256, 0, stream>>>(
      x, xb, npair, w_rel1, w_root1, b_rel1, wt1, u1, v1);

  const int aggBlocks = (N_NODES * 64 + 255) / 256;

  // ---- layer 1: 128 -> 128 ----
  agg_bf16_kernel<128><<<aggBlocks, 256, 0, stream>>>(xb, rowptr, epack, aggb, degw);
  gemm_mfma_kernel<<<392 * 1, 256, 0, stream>>>(aggb, xb, wt1, u1, v1, degw, batch,
                                                hp1, sums1, pmaxk + PO1, pmink + PO1,
                                                psumg + PO1, ppmax, ppmin, ppsum,
                                                N_NODES, 128, 128);
  wt_build_kernel<<<256, 256, 0, stream>>>(w_rel2, w_root2, b_rel2, sums1, gamma1, beta1,
                                           wt2, u2, v2, 128, 256);

  // ---- layer 2: 128 -> 256 ----
  agg_bf16_kernel<128><<<aggBlocks, 256, 0, stream>>>(hp1, rowptr, epack, aggb, nullptr);
  gemm_mfma_kernel<<<392 * 2, 256, 0, stream>>>(aggb, hp1, wt2, u2, v2, degw, batch,
                                                hp2, sums2, pmaxk + PO2, pmink + PO2,
                                                psumg + PO2, ppmax + PP_L1, ppmin + PP_L1,
                                                ppsum + PP_L1, N_NODES, 128, 256);
  wt_build_kernel<<<384, 256, 0, stream>>>(w_rel3, w_root3, b_rel3, sums2, gamma2, beta2,
                                           wt3, u3, v3, 256, 384);

  // ---- layer 3: 256 -> 384 (no hp3 write: pooling fused, output unused) ----
  agg_bf16_kernel<256><<<aggBlocks, 256, 0, stream>>>(hp2, rowptr, epack, aggb, nullptr);
  gemm_mfma_kernel<<<392 * 3, 256, 0, stream>>>(aggb, hp2, wt3, u3, v3, degw, batch,
                                                (unsigned short*)nullptr, sums3,
                                                pmaxk + PO3, pmink + PO3, psumg + PO3,
                                                ppmax + PP_L1 + PP_L2, ppmin + PP_L1 + PP_L2,
                                                ppsum + PP_L1 + PP_L2, N_NODES, 256, 384);

  // ---- fused pool finalize + FC head ----
  finalize_fc_kernel<<<N_GRAPH, 1024, 0, stream>>>(
      pmaxk, pmink, psumg, ppmax, ppmin, ppsum, sums_all,
      gamma1, beta1, gamma2, beta2, gamma3, beta3, gptr, batch,
      w_lin1, b_lin1, w_lin2, b_lin2, w_lin3, b_lin3, outp);
}

// Round 12
// 467.571 us; speedup vs baseline: 1.1833x; 1.0345x over previous
//
#include <hip/hip_runtime.h>
#include <cstdint>
#include <cstddef>

#define N_NODES 50000
#define M_PAD   50048   // 391 * 128
#define MB_TILES 391
#define N_EDGES 800000
#define N_GRAPH 256
#define Z_DIM   2304
#define NREP    16
#define POOL_TOT (N_GRAPH * (128 + 256 + 384))
// privatized pooling partials: per (m_tile, n_tile, gslot{0,1}, half{0,1}) x 128 cols
#define PP_L1 (MB_TILES * 1 * 2 * 2 * 128)   // 200192
#define PP_L2 (MB_TILES * 2 * 2 * 2 * 128)   // 400384
#define PP_L3 (MB_TILES * 3 * 2 * 2 * 128)   // 600576
#define PP_TOT (PP_L1 + PP_L2 + PP_L3)

static constexpr float LEAKY  = 0.01f;
static constexpr float BN_EPS = 1e-5f;
static constexpr float FNEG   = -3.4e38f;
static constexpr float FPOS   =  3.4e38f;

typedef short short8 __attribute__((ext_vector_type(8)));
typedef float floatx4 __attribute__((ext_vector_type(4)));
typedef const __attribute__((address_space(1))) unsigned int* gas_ptr;
typedef __attribute__((address_space(3))) unsigned int* las_ptr;
typedef unsigned long long ull;

__device__ __forceinline__ unsigned short f2b(float f) {
  union { float f; unsigned int u; } v; v.f = f;
  unsigned int u = v.u;
  unsigned int r = (u + 0x7FFFu + ((u >> 16) & 1u)) >> 16;
  return (unsigned short)r;
}
__device__ __forceinline__ float b2f(unsigned short h) {
  union { unsigned int u; float f; } v; v.u = ((unsigned int)h) << 16;
  return v.f;
}
__device__ __forceinline__ unsigned fkey(float x) {
  unsigned k = __float_as_uint(x);
  return k ^ ((k & 0x80000000u) ? 0xFFFFFFFFu : 0x80000000u);
}
__device__ __forceinline__ float kdec(unsigned k) {
  k ^= (k & 0x80000000u) ? 0x80000000u : 0xFFFFFFFFu;
  return __uint_as_float(k);
}
// lower_bound over sorted int array
__device__ __forceinline__ int lbound(const int* __restrict__ b, int n, int val) {
  int lo = 0, hi = n;
  while (lo < hi) { const int mid = (lo + hi) >> 1; if (b[mid] < val) lo = mid + 1; else hi = mid; }
  return lo;
}

// ---------------- one-shot init ----------------

__global__ void init_all_kernel(int* __restrict__ cntR,
                                float* __restrict__ sums_all,
                                unsigned* __restrict__ pmaxk, unsigned* __restrict__ pmink,
                                float* __restrict__ psumg) {
  const int i = blockIdx.x * blockDim.x + threadIdx.x;
  if (i < NREP * N_NODES) cntR[i] = 0;
  if (i < 2 * (128 + 256 + 384)) sums_all[i] = 0.f;
  if (i < POOL_TOT) { pmaxk[i] = 0u; pmink[i] = 0xFFFFFFFFu; psumg[i] = 0.f; }
}

// ---------------- CSR build (replicated histogram/cursor) ----------------

__global__ void hist_rep_kernel(const int* __restrict__ idx, int* __restrict__ cntR, int n) {
  int i = blockIdx.x * blockDim.x + threadIdx.x;
  if (i < n) {
    const int rep = blockIdx.x & (NREP - 1);
    atomicAdd(&cntR[rep * N_NODES + idx[i]], 1);
  }
}

// scan phase 1 fused with replica combine; part[] keeps RAW block totals (no scan2).
__global__ __launch_bounds__(256) void scan1_fused_kernel(int* __restrict__ cntR,
                                                          int* __restrict__ out,
                                                          int* __restrict__ part, int n) {
  __shared__ int sm[256];
  const int t = threadIdx.x;
  const int base = blockIdx.x * 1024 + t * 4;
  int v[4] = {0, 0, 0, 0};
#pragma unroll
  for (int j = 0; j < 4; ++j) {
    const int d = base + j;
    if (d < n) {
      int s = 0;
#pragma unroll
      for (int r = 0; r < NREP; ++r) {
        const int c = cntR[r * N_NODES + d];
        cntR[r * N_NODES + d] = s;
        s += c;
      }
      v[j] = s;
    }
  }
  const int tsum = v[0] + v[1] + v[2] + v[3];
  sm[t] = tsum;
  __syncthreads();
  for (int off = 1; off < 256; off <<= 1) {
    int x = (t >= off) ? sm[t - off] : 0;
    __syncthreads();
    sm[t] += x;
    __syncthreads();
  }
  const int excl = sm[t] - tsum;
  if (base     < n) out[base]     = excl;
  if (base + 1 < n) out[base + 1] = excl + v[0];
  if (base + 2 < n) out[base + 2] = excl + v[0] + v[1];
  if (base + 3 < n) out[base + 3] = excl + v[0] + v[1] + v[2];
  if (t == 255) part[blockIdx.x] = sm[255];
}

// scan3 with inline partial-prefix (replaces scan2): each block computes the exclusive
// prefix of the 49 raw block totals it needs (uniform LDS loop), adds, bumps cursors.
__global__ __launch_bounds__(256) void scan3_cursor_kernel(int* __restrict__ out,
                                                           const int* __restrict__ part,
                                                           int* __restrict__ cntR,
                                                           int n, int nb) {
  __shared__ int ps[64];
  const int t = threadIdx.x;
  if (t < nb) ps[t] = part[t];
  __syncthreads();
  const int pb = blockIdx.x >> 2;  // 1024-element window index of this block
  int myp = 0;
  for (int k = 0; k < pb; ++k) myp += ps[k];
  const int i = blockIdx.x * 256 + t;
  if (i == 0) out[n] = N_EDGES;    // rowptr total: every edge is bucketed
  if (i >= n) return;
  const int rp = out[i] + myp;
  out[i] = rp;
#pragma unroll
  for (int r = 0; r < NREP; ++r) cntR[r * N_NODES + i] += rp;
}

__global__ void bucket_kernel(const int* __restrict__ src, const int* __restrict__ dst,
                              const float* __restrict__ ew, int* __restrict__ cntR,
                              ull* __restrict__ epack, int E) {
  int e = blockIdx.x * blockDim.x + threadIdx.x;
  if (e < E) {
    const int rep = blockIdx.x & (NREP - 1);
    const int d = dst[e];
    const int p = atomicAdd(&cntR[rep * N_NODES + d], 1);
    epack[p] = ((ull)__float_as_uint(ew[e]) << 32) | (unsigned)src[e];
  }
}

// ---------------- prep: fused cast (blocks >= 128) + layer-1 wt_build (blocks < 128) ----

__global__ __launch_bounds__(256) void prep1_kernel(
    const float* __restrict__ x, unsigned short* __restrict__ xb, int npair,
    const float* __restrict__ wrel, const float* __restrict__ wroot,
    const float* __restrict__ brel,
    unsigned short* __restrict__ wt, float* __restrict__ u, float* __restrict__ v) {
  if (blockIdx.x >= 128) {
    const int i = (blockIdx.x - 128) * 256 + threadIdx.x;
    if (i < npair) {
      float2 vv = *(const float2*)(x + 2 * (size_t)i);
      ((unsigned int*)xb)[i] = (unsigned int)f2b(vv.x) | ((unsigned int)f2b(vv.y) << 16);
    }
    return;
  }
  // wt_build for layer 1 (K=128, N=128, no BN folding): u=0, v=brel
  const int n = blockIdx.x;
  const int K = 128, N = 128, K2 = 256;
  for (int k = threadIdx.x; k < K2; k += 256) {
    const int kk = (k < K) ? k : k - K;
    const float w = (k < K) ? wrel[(size_t)kk * N + n] : wroot[(size_t)kk * N + n];
    wt[(size_t)n * K2 + k] = f2b(w);
  }
  if (threadIdx.x == 0) { u[n] = 0.f; v[n] = brel[n]; }
}

// ---------------- fused wt_build (blocks < NW) + aggregation (blocks >= NW) ----------
// Both depend only on the previous layer's gemm; mutually independent -> one dispatch.

template <int D>
__global__ __launch_bounds__(256) void wtagg_kernel(
    const float* __restrict__ wrel, const float* __restrict__ wroot,
    const float* __restrict__ brel, const float* __restrict__ sums_prev,
    const float* __restrict__ gamma_prev, const float* __restrict__ beta_prev,
    unsigned short* __restrict__ wt, float* __restrict__ u, float* __restrict__ v,
    int K, int N, int NW,
    const unsigned short* __restrict__ h, const int* __restrict__ rowptr,
    const ull* __restrict__ epack, unsigned short* __restrict__ agg,
    float* __restrict__ degw_out) {
  if ((int)blockIdx.x < NW) {
    // ---- wt_build path (BN folding; sums_prev always non-null here) ----
    __shared__ float redu[256];
    __shared__ float redv[256];
    const int n = blockIdx.x;
    const int K2 = 2 * K;
    const float inv_n = 1.f / (float)N_NODES;
    float us = 0.f, vs = 0.f;
    for (int k = threadIdx.x; k < K2; k += 256) {
      const int kk = (k < K) ? k : k - K;
      const float w = (k < K) ? wrel[(size_t)kk * N + n] : wroot[(size_t)kk * N + n];
      const float mu  = sums_prev[kk] * inv_n;
      const float var = sums_prev[K + kk] * inv_n - mu * mu;
      const float sc  = rsqrtf(var + BN_EPS) * gamma_prev[kk];
      const float sh  = beta_prev[kk] - mu * sc;
      wt[(size_t)n * K2 + k] = f2b(w * sc);
      if (k < K) us += sh * w; else vs += sh * w;
    }
    redu[threadIdx.x] = us; redv[threadIdx.x] = vs;
    __syncthreads();
    for (int o = 128; o > 0; o >>= 1) {
      if (threadIdx.x < o) {
        redu[threadIdx.x] += redu[threadIdx.x + o];
        redv[threadIdx.x] += redv[threadIdx.x + o];
      }
      __syncthreads();
    }
    if (threadIdx.x == 0) { u[n] = redu[0]; v[n] = brel[n] + redv[0]; }
    return;
  }

  // ---- agg path: MLP-maximized gather (validated r3 structure) ----
  int gid  = (blockIdx.x - NW) * 256 + threadIdx.x;
  int node = gid >> 6;
  int lane = threadIdx.x & 63;
  if (node >= N_NODES) return;
  const int beg = rowptr[node], end = rowptr[node + 1];
  constexpr int NP = D / 128;
  float acc0[NP], acc1[NP];
#pragma unroll
  for (int i = 0; i < NP; ++i) { acc0[i] = 0.f; acc1[i] = 0.f; }
  float wsum = 0.f;

  for (int c0 = beg; c0 < end; c0 += 64) {
    const int cn = min(64, end - c0);
    ull pk = 0;  // pad: src=0, w=0
    if (lane < cn) pk = epack[c0 + lane];
    const int   su = (int)(unsigned)pk;
    const float wf = __uint_as_float((unsigned)(pk >> 32));
    const int ng = (cn + 7) >> 3;
    for (int g = 0; g < ng; ++g) {
      int ss[8]; float wv[8];
#pragma unroll
      for (int j = 0; j < 8; ++j) {
        ss[j] = __shfl(su, g * 8 + j);
        wv[j] = __shfl(wf, g * 8 + j);
      }
      unsigned uu[8][NP];
#pragma unroll
      for (int j = 0; j < 8; ++j) {
        const unsigned int* row = (const unsigned int*)(h + (size_t)ss[j] * D);
#pragma unroll
        for (int i = 0; i < NP; ++i) uu[j][i] = row[lane + 64 * i];
      }
#pragma unroll
      for (int j = 0; j < 8; ++j) {
        wsum += wv[j];
#pragma unroll
        for (int i = 0; i < NP; ++i) {
          acc0[i] += b2f((unsigned short)(uu[j][i] & 0xFFFF)) * wv[j];
          acc1[i] += b2f((unsigned short)(uu[j][i] >> 16)) * wv[j];
        }
      }
    }
  }

  unsigned int* o = (unsigned int*)(agg + (size_t)node * D);
#pragma unroll
  for (int i = 0; i < NP; ++i)
    o[lane + 64 * i] = (unsigned int)f2b(acc0[i]) | ((unsigned int)f2b(acc1[i]) << 16);
  if (degw_out != nullptr && lane == 0) degw_out[node] = wsum;
}

// standalone agg for layer 1 (no wt_build partner: prep1 covers it)
template <int D>
__global__ void agg_bf16_kernel(const unsigned short* __restrict__ h,
                                const int* __restrict__ rowptr,
                                const ull* __restrict__ epack,
                                unsigned short* __restrict__ agg,
                                float* __restrict__ degw_out) {
  int gid  = blockIdx.x * blockDim.x + threadIdx.x;
  int node = gid >> 6;
  int lane = threadIdx.x & 63;
  if (node >= N_NODES) return;
  const int beg = rowptr[node], end = rowptr[node + 1];
  constexpr int NP = D / 128;
  float acc0[NP], acc1[NP];
#pragma unroll
  for (int i = 0; i < NP; ++i) { acc0[i] = 0.f; acc1[i] = 0.f; }
  float wsum = 0.f;

  for (int c0 = beg; c0 < end; c0 += 64) {
    const int cn = min(64, end - c0);
    ull pk = 0;
    if (lane < cn) pk = epack[c0 + lane];
    const int   su = (int)(unsigned)pk;
    const float wf = __uint_as_float((unsigned)(pk >> 32));
    const int ng = (cn + 7) >> 3;
    for (int g = 0; g < ng; ++g) {
      int ss[8]; float wv[8];
#pragma unroll
      for (int j = 0; j < 8; ++j) {
        ss[j] = __shfl(su, g * 8 + j);
        wv[j] = __shfl(wf, g * 8 + j);
      }
      unsigned uu[8][NP];
#pragma unroll
      for (int j = 0; j < 8; ++j) {
        const unsigned int* row = (const unsigned int*)(h + (size_t)ss[j] * D);
#pragma unroll
        for (int i = 0; i < NP; ++i) uu[j][i] = row[lane + 64 * i];
      }
#pragma unroll
      for (int j = 0; j < 8; ++j) {
        wsum += wv[j];
#pragma unroll
        for (int i = 0; i < NP; ++i) {
          acc0[i] += b2f((unsigned short)(uu[j][i] & 0xFFFF)) * wv[j];
          acc1[i] += b2f((unsigned short)(uu[j][i] >> 16)) * wv[j];
        }
      }
    }
  }

  unsigned int* o = (unsigned int*)(agg + (size_t)node * D);
#pragma unroll
  for (int i = 0; i < NP; ++i)
    o[lane + 64 * i] = (unsigned int)f2b(acc0[i]) | ((unsigned int)f2b(acc1[i]) << 16);
  if (degw_out != nullptr && lane == 0) degw_out[node] = wsum;
}

// ---------------- MFMA GEMM with SINGLE-PASS fused pooling (round-10 validated) --------
// LDS 40KB (A triple / B double buffered), raw s_barrier + counted vmcnt(2),
// global_load_lds, XCD-affine tiles, BK=32. col_s/dws/gbs alias the A-buffers
// (dead after K-loop), initialized in the epilogue behind a barrier.

__global__ __launch_bounds__(256) void gemm_mfma_kernel(
    const unsigned short* __restrict__ Aagg, const unsigned short* __restrict__ Ah,
    const unsigned short* __restrict__ Wt,
    const float* __restrict__ u, const float* __restrict__ v,
    const float* __restrict__ degw, const int* __restrict__ batch,
    unsigned short* __restrict__ outH, float* __restrict__ sums,
    unsigned* __restrict__ pmaxk, unsigned* __restrict__ pmink,
    float* __restrict__ psumg,
    float* __restrict__ ppmax, float* __restrict__ ppmin, float* __restrict__ ppsum,
    int M, int K, int N) {
  __shared__ char smem[40960];                                  // 24K A + 16K B
  unsigned short* AsBase = (unsigned short*)smem;               // 3 x 4096 shorts
  unsigned short* BsBase = (unsigned short*)(smem + 24576);     // 2 x 4096 shorts
  float* col_s = (float*)smem;            // epilogue-only, aliases As[0]
  float* dws   = (float*)(smem + 1024);   // epilogue-only
  int*   gbs   = (int*)(smem + 1536);     // epilogue-only

  const int NT = N >> 7;
  const int id = blockIdx.x;
  const int xcd = id & 7;
  const int q   = id >> 3;
  const int m_tile = (q / NT) * 8 + xcd;
  if (m_tile >= MB_TILES) return;
  const int m0 = m_tile * 128;
  const int nt2 = q % NT;
  const int n0 = nt2 * 128;

  const int t  = threadIdx.x;
  const int lane = t & 63;
  const int w    = t >> 6;
  const int wm   = (w & 1) * 64;
  const int wn   = (w >> 1) * 64;
  const int l16  = lane & 15;
  const int lq   = lane >> 4;
  const int K2   = 2 * K;

  const int lrow  = lane >> 2;
  const int lslot = lane & 3;

  floatx4 acc[4][4];
#pragma unroll
  for (int i = 0; i < 4; ++i)
#pragma unroll
    for (int j = 0; j < 4; ++j) acc[i][j] = (floatx4){0.f, 0.f, 0.f, 0.f};

  auto stage_A = [&](unsigned short* Ab, int k0) {
    const unsigned short* Asrc;
    int kbase;
    if (k0 < K) { Asrc = Aagg; kbase = k0; } else { Asrc = Ah; kbase = k0 - K; }
#pragma unroll
    for (int qq = 0; qq < 2; ++qq) {
      const int row = w * 32 + qq * 16 + lrow;
      const int gc  = (lslot ^ ((row >> 1) & 3)) * 8;
      const unsigned short* gA = Asrc + (size_t)(m0 + row) * K + kbase + gc;
      __builtin_amdgcn_global_load_lds((gas_ptr)gA, (las_ptr)(Ab + (w * 32 + qq * 16) * 32),
                                       16, 0, 0);
    }
  };
  auto stage_B = [&](unsigned short* Bb, int k0) {
#pragma unroll
    for (int qq = 0; qq < 2; ++qq) {
      const int row = w * 32 + qq * 16 + lrow;
      const int gc  = (lslot ^ ((row >> 1) & 3)) * 8;
      const unsigned short* gB = Wt + (size_t)(n0 + row) * K2 + k0 + gc;
      __builtin_amdgcn_global_load_lds((gas_ptr)gB, (las_ptr)(Bb + (w * 32 + qq * 16) * 32),
                                       16, 0, 0);
    }
  };

  auto compute = [&](const unsigned short* Ab, const unsigned short* Bb) {
    short8 af[4], bfr[4];
#pragma unroll
    for (int i = 0; i < 4; ++i) {
      const int r = wm + i * 16 + l16;
      af[i] = *(const short8*)(Ab + r * 32 + (lq ^ ((r >> 1) & 3)) * 8);
    }
#pragma unroll
    for (int j = 0; j < 4; ++j) {
      const int r = wn + j * 16 + l16;
      bfr[j] = *(const short8*)(Bb + r * 32 + (lq ^ ((r >> 1) & 3)) * 8);
    }
    __builtin_amdgcn_s_setprio(1);
#pragma unroll
    for (int i = 0; i < 4; ++i)
#pragma unroll
      for (int j = 0; j < 4; ++j)
        acc[i][j] = __builtin_amdgcn_mfma_f32_16x16x32_bf16(af[i], bfr[j], acc[i][j], 0, 0, 0);
    __builtin_amdgcn_s_setprio(0);
  };

  const int NSTEP = K2 >> 5;  // 8 or 16

  unsigned short *A0 = AsBase, *A1 = AsBase + 4096, *A2 = AsBase + 8192;
  unsigned short *B0 = BsBase, *B1 = BsBase + 4096;

  stage_A(A0, 0);
  stage_B(B0, 0);
  stage_A(A1, 1 << 5);

  for (int s = 0; s < NSTEP - 1; ++s) {
    asm volatile("s_waitcnt vmcnt(2)" ::: "memory");
    __builtin_amdgcn_s_barrier();
    __builtin_amdgcn_sched_barrier(0);
    stage_B(B1, (s + 1) << 5);
    if (s + 2 < NSTEP) stage_A(A2, (s + 2) << 5);
    compute(A0, B0);
    unsigned short* tA = A0; A0 = A1; A1 = A2; A2 = tA;
    unsigned short* tB = B0; B0 = B1; B1 = tB;
  }
  asm volatile("s_waitcnt vmcnt(0)" ::: "memory");
  __builtin_amdgcn_s_barrier();
  __builtin_amdgcn_sched_barrier(0);
  compute(A0, B0);

  // ---- epilogue setup: aliased LDS is dead now; barrier before reuse ----
  __syncthreads();
  col_s[t] = 0.f;
  if (t < 128) {
    const int m = m0 + t;
    dws[t] = (m < M) ? degw[m] : 0.f;
    gbs[t] = (m < M) ? batch[m] : -1;
  }
  __syncthreads();

  float uu[4], vv[4];
#pragma unroll
  for (int j = 0; j < 4; ++j) {
    const int n = n0 + wn + j * 16 + l16;
    uu[j] = u[n]; vv[j] = v[n];
  }

  // ---- single-pass epilogue: activation + hp write + BN sums + register pooling ----
  const bool wout = (outH != nullptr);
  const int lastr = min(127, M - 1 - m0);
  const int gmin = gbs[0];
  const int gmax = gbs[lastr];

  float ts[4]  = {0.f, 0.f, 0.f, 0.f};
  float tss[4] = {0.f, 0.f, 0.f, 0.f};
  float px0[4], pn0[4], ps0[4], px1[4], pn1[4], ps1[4];
#pragma unroll
  for (int j = 0; j < 4; ++j) {
    px0[j] = FNEG; pn0[j] = FPOS; ps0[j] = 0.f;
    px1[j] = FNEG; pn1[j] = FPOS; ps1[j] = 0.f;
  }

#pragma unroll
  for (int i = 0; i < 4; ++i) {
    const int lrow2 = wm + i * 16 + lq * 4;
#pragma unroll
    for (int r = 0; r < 4; ++r) {
      const int row = lrow2 + r;
      const bool live = (m0 + row < M);
      const int gv = gbs[row];
      const float dwr = dws[row];
      const bool in0 = live && (gv == gmin);
      const bool in1 = live && (gmax != gmin) && (gv == gmax);
#pragma unroll
      for (int j = 0; j < 4; ++j) {
        const int n = n0 + wn + j * 16 + l16;
        float val = acc[i][j][r] + vv[j] + dwr * uu[j];
        val = val > 0.f ? val : LEAKY * val;
        acc[i][j][r] = val;
        if (live) {
          if (wout) outH[(size_t)(m0 + row) * N + n] = f2b(val);
          ts[j]  += val;
          tss[j] += val * val;
        }
        if (in0) { px0[j] = fmaxf(px0[j], val); pn0[j] = fminf(pn0[j], val); ps0[j] += val; }
        if (in1) { px1[j] = fmaxf(px1[j], val); pn1[j] = fminf(pn1[j], val); ps1[j] += val; }
      }
    }
  }

  const int half = w & 1;
#pragma unroll
  for (int j = 0; j < 4; ++j) {
    float a = ts[j], b = tss[j];
    a += __shfl_xor(a, 16); a += __shfl_xor(a, 32);
    b += __shfl_xor(b, 16); b += __shfl_xor(b, 32);
    float x0 = px0[j], n0v = pn0[j], s0v = ps0[j];
    x0 = fmaxf(x0, __shfl_xor(x0, 16)); x0 = fmaxf(x0, __shfl_xor(x0, 32));
    n0v = fminf(n0v, __shfl_xor(n0v, 16)); n0v = fminf(n0v, __shfl_xor(n0v, 32));
    s0v += __shfl_xor(s0v, 16); s0v += __shfl_xor(s0v, 32);
    float x1 = px1[j], n1v = pn1[j], s1v = ps1[j];
    x1 = fmaxf(x1, __shfl_xor(x1, 16)); x1 = fmaxf(x1, __shfl_xor(x1, 32));
    n1v = fminf(n1v, __shfl_xor(n1v, 16)); n1v = fminf(n1v, __shfl_xor(n1v, 32));
    s1v += __shfl_xor(s1v, 16); s1v += __shfl_xor(s1v, 32);
    if (lq == 0) {
      const int ci = wn + j * 16 + l16;
      atomicAdd(&col_s[ci], a);
      atomicAdd(&col_s[128 + ci], b);
      const size_t tb = (size_t)(m_tile * NT + nt2) * 2;
      const size_t sb0 = ((tb + 0) * 2 + half) * 128 + ci;
      const size_t sb1 = ((tb + 1) * 2 + half) * 128 + ci;
      ppmax[sb0] = x0;  ppmin[sb0] = n0v; ppsum[sb0] = s0v;
      ppmax[sb1] = x1;  ppmin[sb1] = n1v; ppsum[sb1] = s1v;
    }
  }

  // cold fallback: block spans >2 graphs (never for ~195-row graphs) -> global atomics
  if (gmax > gmin + 1) {
    for (int g = gmin + 1; g < gmax; ++g) {
#pragma unroll
      for (int j = 0; j < 4; ++j) {
        float mx = FNEG, mn = FPOS, sm = 0.f;
#pragma unroll
        for (int i = 0; i < 4; ++i) {
          const int lrow2 = wm + i * 16 + lq * 4;
#pragma unroll
          for (int r = 0; r < 4; ++r) {
            const int row = lrow2 + r;
            if (m0 + row < M && gbs[row] == g) {
              const float val = acc[i][j][r];
              mx = fmaxf(mx, val); mn = fminf(mn, val); sm += val;
            }
          }
        }
        mx = fmaxf(mx, __shfl_xor(mx, 16)); mx = fmaxf(mx, __shfl_xor(mx, 32));
        mn = fminf(mn, __shfl_xor(mn, 16)); mn = fminf(mn, __shfl_xor(mn, 32));
        sm += __shfl_xor(sm, 16); sm += __shfl_xor(sm, 32);
        if (lq == 0 && mx > -3.3e38f) {
          const size_t pi = (size_t)g * N + (n0 + wn + j * 16 + l16);
          atomicMax(&pmaxk[pi], fkey(mx));
          atomicMin(&pmink[pi], fkey(mn));
          atomicAdd(&psumg[pi], sm);
        }
      }
    }
  }

  __syncthreads();
  if (t < 128) {
    atomicAdd(&sums[n0 + t], col_s[t]);
    atomicAdd(&sums[N + n0 + t], col_s[128 + t]);
  }
}

// ---------------- fused pool finalize + FC head: one block per graph ----------------
// Graph boundaries found by binary search over sorted batch (replaces hist_batch +
// scan256 dispatches and the gcnt/gptr arrays). zs built in LDS, FC head follows.

__global__ __launch_bounds__(1024) void finalize_fc_kernel(
    const unsigned* __restrict__ pmaxk, const unsigned* __restrict__ pmink,
    const float* __restrict__ psumg,
    const float* __restrict__ ppmax, const float* __restrict__ ppmin,
    const float* __restrict__ ppsum,
    const float* __restrict__ sums_all,
    const float* __restrict__ gamma1, const float* __restrict__ beta1,
    const float* __restrict__ gamma2, const float* __restrict__ beta2,
    const float* __restrict__ gamma3, const float* __restrict__ beta3,
    const int* __restrict__ batch,
    const float* __restrict__ w1, const float* __restrict__ b1,
    const float* __restrict__ w2, const float* __restrict__ b2,
    const float* __restrict__ w3, const float* __restrict__ b3,
    float* __restrict__ out) {
  __shared__ float zs[Z_DIM];
  __shared__ float part[8][128];
  __shared__ float h1s[128];
  __shared__ float red[128][2];
  __shared__ float y2[2];
  __shared__ int gb2[2];
  const int g = blockIdx.x;
  const int t = threadIdx.x;

  if (t < 2) gb2[t] = lbound(batch, N_NODES, g + t);
  __syncthreads();
  const int glo = gb2[0], ghi = gb2[1];
  const int cnt = ghi - glo;

  // ---- phase A: finalize 768 (layer,c) entries -> 2304 zs values ----
  if (t < 768) {
    int C, zoff, c, PO, NTL;
    size_t ppo;
    const float *sums, *gamma, *beta;
    if (t < 128) {
      C = 128; zoff = 0; c = t; PO = 0; NTL = 1; ppo = 0;
      sums = sums_all; gamma = gamma1; beta = beta1;
    } else if (t < 384) {
      C = 256; zoff = 384; c = t - 128; PO = N_GRAPH * 128; NTL = 2; ppo = PP_L1;
      sums = sums_all + 2 * 128; gamma = gamma2; beta = beta2;
    } else {
      C = 384; zoff = 1152; c = t - 384; PO = N_GRAPH * (128 + 256); NTL = 3;
      ppo = PP_L1 + PP_L2;
      sums = sums_all + 2 * (128 + 256); gamma = gamma3; beta = beta3;
    }
    const int i = PO + g * C + c;

    float mx = FNEG, mn = FPOS, sm = psumg[i];
    {
      const unsigned pk = pmaxk[i];
      if (pk != 0u) mx = kdec(pk);
      const unsigned nk = pmink[i];
      if (nk != 0xFFFFFFFFu) mn = kdec(nk);
    }
    if (cnt > 0) {
      const int mt_lo = glo >> 7;
      const int mt_hi = (ghi - 1) >> 7;
      const int nt = c >> 7, cc = c & 127;
      for (int mt = mt_lo; mt <= mt_hi; ++mt) {
        const int g0 = batch[mt << 7];
        int grel = (g == g0) ? 0 : -1;
        if (grel < 0) {
          const int lastm = min((mt << 7) + 127, N_NODES - 1);
          if (g == batch[lastm]) grel = 1;
        }
        if (grel >= 0) {
          const size_t b0 = ppo + (((size_t)(mt * NTL + nt) * 2 + grel) * 2 + 0) * 128 + cc;
          const size_t b1v = b0 + 128;
          mx = fmaxf(mx, fmaxf(ppmax[b0], ppmax[b1v]));
          mn = fminf(mn, fminf(ppmin[b0], ppmin[b1v]));
          sm += ppsum[b0] + ppsum[b1v];
        }
      }
    }

    const float inv_n = 1.f / (float)N_NODES;
    const float mu  = sums[c] * inv_n;
    const float var = sums[C + c] * inv_n - mu * mu;
    const float sc  = rsqrtf(var + BN_EPS) * gamma[c];
    const float sh  = beta[c] - mu * sc;
    const float zmax = (sc >= 0.f ? mx : mn) * sc + sh;
    const float zsum = sm * sc + (float)cnt * sh;
    zs[zoff + c]         = (cnt > 0) ? zmax : 0.f;
    zs[zoff + C + c]     = zsum / (float)(cnt > 0 ? cnt : 1);
    zs[zoff + 2 * C + c] = zsum;
  }
  __syncthreads();

  // ---- phase B: FC head (validated structure) ----
  const int c  = t & 127;
  const int ks = t >> 7;
  constexpr int KCH = Z_DIM / 8;
  const int k0 = ks * KCH;
  float acc = 0.f;
#pragma unroll 4
  for (int k = k0; k < k0 + KCH; ++k) acc += zs[k] * w1[(size_t)k * 128 + c];
  part[ks][c] = acc;
  __syncthreads();

  if (t < 128) {
    float s = b1[t];
#pragma unroll
    for (int i = 0; i < 8; ++i) s += part[i][t];
    h1s[t] = fmaxf(s, 0.f);
  }
  __syncthreads();
  if (t < 128) {
    red[t][0] = h1s[t] * w2[t * 2 + 0];
    red[t][1] = h1s[t] * w2[t * 2 + 1];
  }
  __syncthreads();
  if (t < 2) {
    float s = b2[t];
    for (int k = 0; k < 128; ++k) s += red[k][t];
    y2[t] = fmaxf(s, 0.f);
  }
  __syncthreads();
  if (t == 0) {
    const float z0 = y2[0] * w3[0] + y2[1] * w3[2] + b3[0];
    const float z1 = y2[0] * w3[1] + y2[1] * w3[3] + b3[1];
    const float m  = fmaxf(z0, z1);
    const float lse = m + logf(expf(z0 - m) + expf(z1 - m));
    out[g * 2 + 0] = z0 - lse;
    out[g * 2 + 1] = z1 - lse;
  }
}

// ---------------- launch ----------------

extern "C" void kernel_launch(void* const* d_in, const int* in_sizes, int n_in,
                              void* d_out, int out_size, void* d_ws, size_t ws_size,
                              hipStream_t stream) {
  (void)in_sizes; (void)n_in; (void)out_size; (void)ws_size;
  const float* x        = (const float*)d_in[0];
  const int*   eidx     = (const int*)d_in[1];
  const int*   batch    = (const int*)d_in[2];
  const float* eattr    = (const float*)d_in[3];
  const float* w_rel1   = (const float*)d_in[4];
  const float* b_rel1   = (const float*)d_in[5];
  const float* w_root1  = (const float*)d_in[6];
  const float* w_rel2   = (const float*)d_in[7];
  const float* b_rel2   = (const float*)d_in[8];
  const float* w_root2  = (const float*)d_in[9];
  const float* w_rel3   = (const float*)d_in[10];
  const float* b_rel3   = (const float*)d_in[11];
  const float* w_root3  = (const float*)d_in[12];
  const float* gamma1   = (const float*)d_in[13];
  const float* beta1    = (const float*)d_in[14];
  const float* gamma2   = (const float*)d_in[15];
  const float* beta2    = (const float*)d_in[16];
  const float* gamma3   = (const float*)d_in[17];
  const float* beta3    = (const float*)d_in[18];
  const float* w_lin1   = (const float*)d_in[19];
  const float* b_lin1   = (const float*)d_in[20];
  const float* w_lin2   = (const float*)d_in[21];
  const float* b_lin2   = (const float*)d_in[22];
  const float* w_lin3   = (const float*)d_in[23];
  const float* b_lin3   = (const float*)d_in[24];

  const int* src = eidx;
  const int* dst = eidx + N_EDGES;
  float* outp = (float*)d_out;

  char* ws = (char*)d_ws;
  size_t off = 0;
  auto alloc = [&](size_t bytes) -> void* {
    void* p = ws + off;
    off += (bytes + 255) & ~(size_t)255;
    return p;
  };
  int*   rowptr = (int*)alloc((N_NODES + 1) * sizeof(int));
  int*   cntR   = (int*)alloc((size_t)NREP * N_NODES * sizeof(int));
  int*   part   = (int*)alloc(256 * sizeof(int));
  ull*   epack  = (ull*)alloc((size_t)N_EDGES * sizeof(ull));
  float* degw   = (float*)alloc(N_NODES * sizeof(float));
  float* sums_all = (float*)alloc(2 * (128 + 256 + 384) * sizeof(float));
  unsigned* pmaxk = (unsigned*)alloc((size_t)POOL_TOT * 4);
  unsigned* pmink = (unsigned*)alloc((size_t)POOL_TOT * 4);
  float*    psumg = (float*)alloc((size_t)POOL_TOT * 4);
  float* ppmax = (float*)alloc((size_t)PP_TOT * 4);
  float* ppmin = (float*)alloc((size_t)PP_TOT * 4);
  float* ppsum = (float*)alloc((size_t)PP_TOT * 4);
  unsigned short* xb   = (unsigned short*)alloc((size_t)M_PAD * 128 * 2);
  unsigned short* hp1  = (unsigned short*)alloc((size_t)M_PAD * 128 * 2);
  unsigned short* hp2  = (unsigned short*)alloc((size_t)M_PAD * 256 * 2);
  unsigned short* aggb = (unsigned short*)alloc((size_t)M_PAD * 256 * 2);
  unsigned short* wt1 = (unsigned short*)alloc((size_t)128 * 256 * 2);
  unsigned short* wt2 = (unsigned short*)alloc((size_t)256 * 256 * 2);
  unsigned short* wt3 = (unsigned short*)alloc((size_t)384 * 512 * 2);
  float* u1 = (float*)alloc(128 * sizeof(float));
  float* v1 = (float*)alloc(128 * sizeof(float));
  float* u2 = (float*)alloc(256 * sizeof(float));
  float* v2 = (float*)alloc(256 * sizeof(float));
  float* u3 = (float*)alloc(384 * sizeof(float));
  float* v3 = (float*)alloc(384 * sizeof(float));

  float* sums1 = sums_all;
  float* sums2 = sums_all + 2 * 128;
  float* sums3 = sums_all + 2 * (128 + 256);
  const int PO1 = 0, PO2 = N_GRAPH * 128, PO3 = N_GRAPH * (128 + 256);

  const int EB = (N_EDGES + 255) / 256;
  const int NB = (N_NODES + 255) / 256;
  const int SB = (N_NODES + 1023) / 1024;

  init_all_kernel<<<(NREP * N_NODES + 255) / 256, 256, 0, stream>>>(
      cntR, sums_all, pmaxk, pmink, psumg);

  // ---- CSR by dst (scan2 folded into scan3; graph ptrs now binary-searched) ----
  hist_rep_kernel<<<EB, 256, 0, stream>>>(dst, cntR, N_EDGES);
  scan1_fused_kernel<<<SB, 256, 0, stream>>>(cntR, rowptr, part, N_NODES);
  scan3_cursor_kernel<<<NB, 256, 0, stream>>>(rowptr, part, cntR, N_NODES, SB);
  bucket_kernel<<<EB, 256, 0, stream>>>(src, dst, eattr, cntR, epack, N_EDGES);

  // ---- prep: fused cast + layer-1 wt_build ----
  const int npair = N_NODES * 128 / 2;
  prep1_kernel<<<128 + (npair + 255) / 256, 256, 0, stream>>>(
      x, xb, npair, w_rel1, w_root1, b_rel1, wt1, u1, v1);

  const int aggBlocks = (N_NODES * 64 + 255) / 256;

  // ---- layer 1: 128 -> 128 ----
  agg_bf16_kernel<128><<<aggBlocks, 256, 0, stream>>>(xb, rowptr, epack, aggb, degw);
  gemm_mfma_kernel<<<392 * 1, 256, 0, stream>>>(aggb, xb, wt1, u1, v1, degw, batch,
                                                hp1, sums1, pmaxk + PO1, pmink + PO1,
                                                psumg + PO1, ppmax, ppmin, ppsum,
                                                N_NODES, 128, 128);

  // ---- layer 2: fused wt_build2 + agg2, then gemm2 ----
  wtagg_kernel<128><<<256 + aggBlocks, 256, 0, stream>>>(
      w_rel2, w_root2, b_rel2, sums1, gamma1, beta1, wt2, u2, v2, 128, 256, 256,
      hp1, rowptr, epack, aggb, nullptr);
  gemm_mfma_kernel<<<392 * 2, 256, 0, stream>>>(aggb, hp1, wt2, u2, v2, degw, batch,
                                                hp2, sums2, pmaxk + PO2, pmink + PO2,
                                                psumg + PO2, ppmax + PP_L1, ppmin + PP_L1,
                                                ppsum + PP_L1, N_NODES, 128, 256);

  // ---- layer 3: fused wt_build3 + agg3, then gemm3 (no hp3 write) ----
  wtagg_kernel<256><<<384 + aggBlocks, 256, 0, stream>>>(
      w_rel3, w_root3, b_rel3, sums2, gamma2, beta2, wt3, u3, v3, 256, 384, 384,
      hp2, rowptr, epack, aggb, nullptr);
  gemm_mfma_kernel<<<392 * 3, 256, 0, stream>>>(aggb, hp2, wt3, u3, v3, degw, batch,
                                                (unsigned short*)nullptr, sums3,
                                                pmaxk + PO3, pmink + PO3, psumg + PO3,
                                                ppmax + PP_L1 + PP_L2, ppmin + PP_L1 + PP_L2,
                                                ppsum + PP_L1 + PP_L2, N_NODES, 256, 384);

  // ---- fused pool finalize + FC head (binary-search graph bounds) ----
  finalize_fc_kernel<<<N_GRAPH, 1024, 0, stream>>>(
      pmaxk, pmink, psumg, ppmax, ppmin, ppsum, sums_all,
      gamma1, beta1, gamma2, beta2, gamma3, beta3, batch,
      w_lin1, b_lin1, w_lin2, b_lin2, w_lin3, b_lin3, outp);
}